// Round 2
// baseline (364.763 us; speedup 1.0000x reference)
//
#include <hip/hip_runtime.h>
#include <hip/hip_bf16.h>

// Problem constants
// B=2, S=2048, D=1024, H=16, HD=64, M = B*S = 4096

typedef __attribute__((ext_vector_type(8))) short short8;   // 8 bf16 = 4 VGPR (MFMA A/B frag)
typedef __attribute__((ext_vector_type(4))) short short4v;  // 4 bf16
typedef __attribute__((ext_vector_type(4))) float f32x4;    // MFMA C/D frag

static __device__ __forceinline__ short f2bf(float f) {
    union { float f; unsigned u; } c; c.f = f;
    unsigned r = c.u + 0x7fff + ((c.u >> 16) & 1);   // RNE; inputs are finite
    return (short)(r >> 16);
}

// packed f32x2 -> bf16x2 (compiler emits v_cvt_pk_bf16_f32)
static __device__ __forceinline__ unsigned pk_bf16(float a, float b) {
    union { __hip_bfloat162 h; unsigned u; } c;
    c.h = __float22bfloat162_rn(make_float2(a, b));
    return c.u;
}

// ---------------------------------------------------------------------------
// Weight transpose + bf16 cast: W[K=1024][N=1024] f32 -> Wt[N][K] bf16.
// ---------------------------------------------------------------------------
__global__ __launch_bounds__(256) void wtrans(
    const float* __restrict__ W0, const float* __restrict__ W1,
    const float* __restrict__ W2, const float* __restrict__ W3,
    short* __restrict__ Out)
{
    const float* W = blockIdx.z == 0 ? W0 : blockIdx.z == 1 ? W1
                   : blockIdx.z == 2 ? W2 : W3;
    short* O = Out + ((size_t)blockIdx.z << 20);
    __shared__ float tile[32][33];
    const int k0 = blockIdx.x * 32, n0 = blockIdx.y * 32;
    const int tx = threadIdx.x, ty = threadIdx.y;  // (32,8)
    #pragma unroll
    for (int j = 0; j < 32; j += 8)
        tile[ty + j][tx] = W[(k0 + ty + j) * 1024 + n0 + tx];
    __syncthreads();
    #pragma unroll
    for (int j = 0; j < 32; j += 8)
        O[(n0 + ty + j) * 1024 + k0 + tx] = f2bf(tile[tx][ty + j]);
}

// ---------------------------------------------------------------------------
// GEMM: Out = scale * (A[4096x1024] @ Wt^T + bias). Wt is [N][K] bf16.
// (unchanged from round 1 — known-correct; gemm optimization is next round)
// ---------------------------------------------------------------------------
template<int AMODE, int OMODE>
__global__ __launch_bounds__(256) void gemm_k(
    const void* __restrict__ Ap, const short* __restrict__ Bt,
    const float* __restrict__ bias, void* __restrict__ Out, float scale)
{
    __shared__ short Al[128][40];
    __shared__ short Bl[128][40];
    const int t = threadIdx.x;
    const int m0 = blockIdx.x * 128, n0 = blockIdx.y * 128;
    const int lane = t & 63, w = t >> 6;
    const int lm = lane & 15, lg = lane >> 4;
    const int wr = w >> 1, wc = w & 1;

    f32x4 acc[4][4] = {};

    for (int k0 = 0; k0 < 1024; k0 += 32) {
        if (AMODE == 0) {
            const float* A = (const float*)Ap;
            const int r = t >> 3, c = t & 7;
            #pragma unroll
            for (int j = 0; j < 4; ++j) {
                const float4 v = *(const float4*)(A + (m0 + r + j * 32) * 1024 + k0 + c * 4);
                short4v sv;
                sv[0] = f2bf(v.x); sv[1] = f2bf(v.y); sv[2] = f2bf(v.z); sv[3] = f2bf(v.w);
                *(short4v*)&Al[r + j * 32][c * 4] = sv;
            }
        } else {
            const short* A = (const short*)Ap;
            const int r = t >> 2, c = t & 3;
            #pragma unroll
            for (int j = 0; j < 2; ++j)
                *(short8*)&Al[r + j * 64][c * 8] =
                    *(const short8*)(A + (m0 + r + j * 64) * 1024 + k0 + c * 8);
        }
        {
            const int r = t >> 2, c = t & 3;
            #pragma unroll
            for (int j = 0; j < 2; ++j)
                *(short8*)&Bl[r + j * 64][c * 8] =
                    *(const short8*)(Bt + (n0 + r + j * 64) * 1024 + k0 + c * 8);
        }
        __syncthreads();

        short8 af[4], bfr[4];
        #pragma unroll
        for (int mf = 0; mf < 4; ++mf)
            af[mf] = *(const short8*)&Al[wr * 64 + mf * 16 + lm][lg * 8];
        #pragma unroll
        for (int nf = 0; nf < 4; ++nf)
            bfr[nf] = *(const short8*)&Bl[wc * 64 + nf * 16 + lm][lg * 8];
        #pragma unroll
        for (int mf = 0; mf < 4; ++mf)
            #pragma unroll
            for (int nf = 0; nf < 4; ++nf)
                acc[mf][nf] = __builtin_amdgcn_mfma_f32_16x16x32_bf16(
                    af[mf], bfr[nf], acc[mf][nf], 0, 0, 0);
        __syncthreads();
    }

    #pragma unroll
    for (int mf = 0; mf < 4; ++mf) {
        const int mb = m0 + wr * 64 + mf * 16 + lg * 4;
        #pragma unroll
        for (int nf = 0; nf < 4; ++nf) {
            const int n = n0 + wc * 64 + nf * 16 + lm;
            const float bs = bias[n];
            if (OMODE == 2) {
                float* O = (float*)Out;
                #pragma unroll
                for (int i = 0; i < 4; ++i)
                    O[(mb + i) * 1024 + n] = scale * (acc[mf][nf][i] + bs);
            } else if (OMODE == 0) {
                short* O = (short*)Out;
                #pragma unroll
                for (int i = 0; i < 4; ++i) {
                    const int m = mb + i;
                    const int addr = (((m >> 11) * 16 + (n >> 6)) * 2048 + (m & 2047)) * 64 + (n & 63);
                    O[addr] = f2bf(scale * (acc[mf][nf][i] + bs));
                }
            } else {  // OMODE 1: Vt [B,H,64,S]
                short* O = (short*)Out;
                short4v sv;
                #pragma unroll
                for (int i = 0; i < 4; ++i)
                    sv[i] = f2bf(scale * (acc[mf][nf][i] + bs));
                const int addr = (((mb >> 11) * 16 + (n >> 6)) * 64 + (n & 63)) * 2048 + (mb & 2047);
                *(short4v*)&O[addr] = sv;
            }
        }
    }
}

// ---------------------------------------------------------------------------
// Flash attention, fully-swapped layout, barrier-free.
// Q[B,H,S,64] (pre-scaled 1/8), K[B,H,S,64], V^T[B,H,64,S], all bf16.
// Block = (64 q-rows, one bh); 4 waves x 16 q-rows. KBLK=64.
// Swapped QK^T: sa = mfma(K_frag, Q_frag) = S^T -> each lane owns the FULL
// 64-key row for query q=lane&15 (16 in-reg partials + 2 shfl_xor to reduce
// across the 4 lg-lanes). Swapped PV: o = mfma(V^T_frag, P^T_frag) = ctx^T ->
// rescale/normalize are pure per-lane. K/V fragments read directly from
// global (tiles are L1/L2-resident; all 4 waves read identical addresses) —
// no K/V LDS, no __syncthreads anywhere. P goes through a per-wave
// XOR-swizzled LDS buffer (write 8B packed, read b128).
// ---------------------------------------------------------------------------
__global__ __launch_bounds__(256) void attn_k(
    const short* __restrict__ Q, const short* __restrict__ K,
    const short* __restrict__ V, short* __restrict__ Ctx)
{
    __shared__ short Pl[4][16][64];
    const int t = threadIdx.x;
    const int qt = blockIdx.x, bh = blockIdx.y;
    const int lane = t & 63, w = t >> 6;
    const int lm = lane & 15, lg = lane >> 4;
    const int swz = (lm & 7) << 3;          // 16B-granule XOR swizzle (short units)

    const int qrow = qt * 64 + w * 16 + lm;
    short8 qf[2];
    #pragma unroll
    for (int ks = 0; ks < 2; ++ks)
        qf[ks] = *(const short8*)(Q + ((size_t)bh * 2048 + qrow) * 64 + ks * 32 + lg * 8);

    float m_run = -3e38f, l_run = 0.f;
    f32x4 o_acc[4] = {};

    const short* Kg = K + ((size_t)bh * 2048 + lm) * 64 + lg * 8;
    const short* Vg = V + ((size_t)bh * 64 + lm) * 2048 + lg * 8;
    short* prow = &Pl[w][lm][0];

    for (int kt = 0; kt < 32; ++kt) {
        const int kv0 = kt * 64;

        // K fragments (A-operand of S^T): row = key, k = head-dim
        short8 kf[4][2];
        #pragma unroll
        for (int nf = 0; nf < 4; ++nf)
            #pragma unroll
            for (int ks = 0; ks < 2; ++ks)
                kf[nf][ks] = *(const short8*)(Kg + (size_t)(kv0 + nf * 16) * 64 + ks * 32);

        // S^T = K Q^T : lane holds q = lm, keys nf*16 + lg*4 + i
        f32x4 sa[4] = {};
        #pragma unroll
        for (int nf = 0; nf < 4; ++nf)
            #pragma unroll
            for (int ks = 0; ks < 2; ++ks)
                sa[nf] = __builtin_amdgcn_mfma_f32_16x16x32_bf16(kf[nf][ks], qf[ks], sa[nf], 0, 0, 0);

        // V^T fragments (A-operand of ctx^T): issue now, consumed after softmax
        short8 vf[4][2];
        #pragma unroll
        for (int nf = 0; nf < 4; ++nf)
            #pragma unroll
            for (int ks = 0; ks < 2; ++ks)
                vf[nf][ks] = *(const short8*)(Vg + (size_t)(nf * 16) * 2048 + kv0 + ks * 32);

        // ---- online softmax, per-lane row (q = lm) ----
        float mt = sa[0][0];
        #pragma unroll
        for (int nf = 0; nf < 4; ++nf)
            #pragma unroll
            for (int i = 0; i < 4; ++i)
                mt = fmaxf(mt, sa[nf][i]);
        mt = fmaxf(mt, __shfl_xor(mt, 16));
        mt = fmaxf(mt, __shfl_xor(mt, 32));
        const float mn = fmaxf(m_run, mt);
        const float alpha = __expf(m_run - mn);
        float rs = 0.f;
        #pragma unroll
        for (int nf = 0; nf < 4; ++nf)
            #pragma unroll
            for (int i = 0; i < 4; ++i) {
                const float e = __expf(sa[nf][i] - mn);
                sa[nf][i] = e;
                rs += e;
            }
        rs += __shfl_xor(rs, 16);
        rs += __shfl_xor(rs, 32);
        l_run = l_run * alpha + rs;
        m_run = mn;
        #pragma unroll
        for (int nf = 0; nf < 4; ++nf)
            #pragma unroll
            for (int i = 0; i < 4; ++i)
                o_acc[nf][i] *= alpha;

        // ---- P^T -> per-wave swizzled LDS (packed bf16, 8B writes) ----
        #pragma unroll
        for (int nf = 0; nf < 4; ++nf) {
            uint2 pv;
            pv.x = pk_bf16(sa[nf][0], sa[nf][1]);
            pv.y = pk_bf16(sa[nf][2], sa[nf][3]);
            *(uint2*)(prow + ((nf * 16 + lg * 4) ^ swz)) = pv;
        }
        short8 pf[2];
        #pragma unroll
        for (int ks = 0; ks < 2; ++ks)
            pf[ks] = *(const short8*)(prow + ((ks * 32 + lg * 8) ^ swz));

        // ---- ctx^T += V^T P^T : lane holds q = lm, d = nf*16 + lg*4 + i ----
        #pragma unroll
        for (int nf = 0; nf < 4; ++nf)
            #pragma unroll
            for (int ks = 0; ks < 2; ++ks)
                o_acc[nf] = __builtin_amdgcn_mfma_f32_16x16x32_bf16(vf[nf][ks], pf[ks], o_acc[nf], 0, 0, 0);
    }

    // epilogue: ctx[b][q][h*64 + d], d = nf*16 + lg*4 + i -> 8B vector writes
    const float inv = 1.f / l_run;
    const int b = bh >> 4, h = bh & 15;
    short* outp = Ctx + ((size_t)b * 2048 + qrow) * 1024 + h * 64 + lg * 4;
    #pragma unroll
    for (int nf = 0; nf < 4; ++nf) {
        uint2 pk;
        pk.x = pk_bf16(o_acc[nf][0] * inv, o_acc[nf][1] * inv);
        pk.y = pk_bf16(o_acc[nf][2] * inv, o_acc[nf][3] * inv);
        *(uint2*)(outp + nf * 16) = pk;
    }
}

// ---------------------------------------------------------------------------
extern "C" void kernel_launch(void* const* d_in, const int* in_sizes, int n_in,
                              void* d_out, int out_size, void* d_ws, size_t ws_size,
                              hipStream_t stream)
{
    const float* query  = (const float*)d_in[0];
    const float* key_in = (const float*)d_in[1];
    const float* value  = (const float*)d_in[2];
    const float* Wq = (const float*)d_in[3];
    const float* bq = (const float*)d_in[4];
    const float* Wk = (const float*)d_in[5];
    const float* bk = (const float*)d_in[6];
    const float* Wv = (const float*)d_in[7];
    const float* bv = (const float*)d_in[8];
    const float* Wo = (const float*)d_in[9];
    const float* bo = (const float*)d_in[10];
    float* out = (float*)d_out;

    char* ws = (char*)d_ws;
    short* Wt  = (short*)(ws);              // 4 x 2MB bf16 transposed weights
    short* Qh  = (short*)(ws + (8  << 20)); // [B,H,S,64]  8MB (pre-scaled 1/8)
    short* Kh  = (short*)(ws + (16 << 20)); // [B,H,S,64]  8MB
    short* Vt  = (short*)(ws + (24 << 20)); // [B,H,64,S]  8MB
    short* Ctx = (short*)(ws + (32 << 20)); // [B,S,D]     8MB

    hipLaunchKernelGGL(wtrans, dim3(32, 32, 4), dim3(32, 8), 0, stream,
                       Wq, Wk, Wv, Wo, Wt);
    hipLaunchKernelGGL((gemm_k<0, 0>), dim3(32, 8), dim3(256), 0, stream,
                       query, Wt, bq, Qh, 0.125f);
    hipLaunchKernelGGL((gemm_k<0, 0>), dim3(32, 8), dim3(256), 0, stream,
                       key_in, Wt + (1 << 20), bk, Kh, 1.0f);
    hipLaunchKernelGGL((gemm_k<0, 1>), dim3(32, 8), dim3(256), 0, stream,
                       value, Wt + (2 << 20), bv, Vt, 1.0f);
    hipLaunchKernelGGL(attn_k, dim3(32, 32), dim3(256), 0, stream,
                       Qh, Kh, Vt, Ctx);
    hipLaunchKernelGGL((gemm_k<1, 2>), dim3(32, 8), dim3(256), 0, stream,
                       Ctx, Wt + (3 << 20), bo, out, 1.0f);
}

// Round 3
// 211.009 us; speedup vs baseline: 1.7287x; 1.7287x over previous
//
#include <hip/hip_runtime.h>
#include <hip/hip_bf16.h>

// Problem constants
// B=2, S=2048, D=1024, H=16, HD=64, M = B*S = 4096

typedef __attribute__((ext_vector_type(8))) short short8;   // 8 bf16 = 4 VGPR (MFMA A/B frag)
typedef __attribute__((ext_vector_type(4))) short short4v;  // 4 bf16
typedef __attribute__((ext_vector_type(4))) float f32x4;    // MFMA C/D frag

static __device__ __forceinline__ short f2bf(float f) {
    union { float f; unsigned u; } c; c.f = f;
    unsigned r = c.u + 0x7fff + ((c.u >> 16) & 1);   // RNE; inputs are finite
    return (short)(r >> 16);
}

// packed f32x2 -> bf16x2 (compiler emits v_cvt_pk_bf16_f32)
static __device__ __forceinline__ unsigned pk_bf16(float a, float b) {
    union { __hip_bfloat162 h; unsigned u; } c;
    c.h = __float22bfloat162_rn(make_float2(a, b));
    return c.u;
}

// ---------------------------------------------------------------------------
// Weight transpose + bf16 cast: W[K=1024][N=1024] f32 -> Wt[N][K] bf16.
// ---------------------------------------------------------------------------
__global__ __launch_bounds__(256) void wtrans(
    const float* __restrict__ W0, const float* __restrict__ W1,
    const float* __restrict__ W2, const float* __restrict__ W3,
    short* __restrict__ Out)
{
    const float* W = blockIdx.z == 0 ? W0 : blockIdx.z == 1 ? W1
                   : blockIdx.z == 2 ? W2 : W3;
    short* O = Out + ((size_t)blockIdx.z << 20);
    __shared__ float tile[32][33];
    const int k0 = blockIdx.x * 32, n0 = blockIdx.y * 32;
    const int tx = threadIdx.x, ty = threadIdx.y;  // (32,8)
    #pragma unroll
    for (int j = 0; j < 32; j += 8)
        tile[ty + j][tx] = W[(k0 + ty + j) * 1024 + n0 + tx];
    __syncthreads();
    #pragma unroll
    for (int j = 0; j < 32; j += 8)
        O[(n0 + ty + j) * 1024 + k0 + tx] = f2bf(tile[tx][ty + j]);
}

// ---------------------------------------------------------------------------
// GEMM: Out = scale * (A[4096x1024] @ Wt^T + bias). Wt is [N][K] bf16.
// (unchanged — known-correct; gemm optimization is a later round)
// ---------------------------------------------------------------------------
template<int AMODE, int OMODE>
__global__ __launch_bounds__(256) void gemm_k(
    const void* __restrict__ Ap, const short* __restrict__ Bt,
    const float* __restrict__ bias, void* __restrict__ Out, float scale)
{
    __shared__ short Al[128][40];
    __shared__ short Bl[128][40];
    const int t = threadIdx.x;
    const int m0 = blockIdx.x * 128, n0 = blockIdx.y * 128;
    const int lane = t & 63, w = t >> 6;
    const int lm = lane & 15, lg = lane >> 4;
    const int wr = w >> 1, wc = w & 1;

    f32x4 acc[4][4] = {};

    for (int k0 = 0; k0 < 1024; k0 += 32) {
        if (AMODE == 0) {
            const float* A = (const float*)Ap;
            const int r = t >> 3, c = t & 7;
            #pragma unroll
            for (int j = 0; j < 4; ++j) {
                const float4 v = *(const float4*)(A + (m0 + r + j * 32) * 1024 + k0 + c * 4);
                short4v sv;
                sv[0] = f2bf(v.x); sv[1] = f2bf(v.y); sv[2] = f2bf(v.z); sv[3] = f2bf(v.w);
                *(short4v*)&Al[r + j * 32][c * 4] = sv;
            }
        } else {
            const short* A = (const short*)Ap;
            const int r = t >> 2, c = t & 3;
            #pragma unroll
            for (int j = 0; j < 2; ++j)
                *(short8*)&Al[r + j * 64][c * 8] =
                    *(const short8*)(A + (m0 + r + j * 64) * 1024 + k0 + c * 8);
        }
        {
            const int r = t >> 2, c = t & 3;
            #pragma unroll
            for (int j = 0; j < 2; ++j)
                *(short8*)&Bl[r + j * 64][c * 8] =
                    *(const short8*)(Bt + (n0 + r + j * 64) * 1024 + k0 + c * 8);
        }
        __syncthreads();

        short8 af[4], bfr[4];
        #pragma unroll
        for (int mf = 0; mf < 4; ++mf)
            af[mf] = *(const short8*)&Al[wr * 64 + mf * 16 + lm][lg * 8];
        #pragma unroll
        for (int nf = 0; nf < 4; ++nf)
            bfr[nf] = *(const short8*)&Bl[wc * 64 + nf * 16 + lm][lg * 8];
        #pragma unroll
        for (int mf = 0; mf < 4; ++mf)
            #pragma unroll
            for (int nf = 0; nf < 4; ++nf)
                acc[mf][nf] = __builtin_amdgcn_mfma_f32_16x16x32_bf16(
                    af[mf], bfr[nf], acc[mf][nf], 0, 0, 0);
        __syncthreads();
    }

    #pragma unroll
    for (int mf = 0; mf < 4; ++mf) {
        const int mb = m0 + wr * 64 + mf * 16 + lg * 4;
        #pragma unroll
        for (int nf = 0; nf < 4; ++nf) {
            const int n = n0 + wc * 64 + nf * 16 + lm;
            const float bs = bias[n];
            if (OMODE == 2) {
                float* O = (float*)Out;
                #pragma unroll
                for (int i = 0; i < 4; ++i)
                    O[(mb + i) * 1024 + n] = scale * (acc[mf][nf][i] + bs);
            } else if (OMODE == 0) {
                short* O = (short*)Out;
                #pragma unroll
                for (int i = 0; i < 4; ++i) {
                    const int m = mb + i;
                    const int addr = (((m >> 11) * 16 + (n >> 6)) * 2048 + (m & 2047)) * 64 + (n & 63);
                    O[addr] = f2bf(scale * (acc[mf][nf][i] + bs));
                }
            } else {  // OMODE 1: Vt [B,H,64,S]
                short* O = (short*)Out;
                short4v sv;
                #pragma unroll
                for (int i = 0; i < 4; ++i)
                    sv[i] = f2bf(scale * (acc[mf][nf][i] + bs));
                const int addr = (((mb >> 11) * 16 + (n >> 6)) * 64 + (n & 63)) * 2048 + (mb & 2047);
                *(short4v*)&O[addr] = sv;
            }
        }
    }
}

// ---------------------------------------------------------------------------
// Flash attention v3: LDS-staged K/V (double-buffered, 1 barrier/tile) +
// fully-swapped MFMA layout (per-lane online softmax).
// Q[B,H,S,64] (pre-scaled 1/8), K[B,H,S,64], V^T[B,H,64,S], all bf16.
// Block = 64 q-rows x one bh; 4 waves x 16 q-rows; KVBLK=64.
//
// Staging: linear [64][64] bf16 tiles, XOR chunk-swizzle (chunk ^= row&7,
// 16B chunks) applied on BOTH ds_write and ds_read (row stride = 128B would
// otherwise be a 16-way bank conflict on fragment reads). T14 split: global
// loads for tile kt+1 issue at top of iteration kt, ds_writes land after the
// softmax — HBM/L2 latency hides under QK+softmax, one __syncthreads/tile.
//
// Swapped QK^T (sa = mfma(K,Q) = S^T): lane owns the full 64-key row of
// query q=lane&15 -> softmax = in-reg max/sum + 2 shfl_xor. Swapped PV
// (o = mfma(V^T, P^T) = ctx^T): rescale/normalize per-lane. P round-trips
// through a per-wave XOR-swizzled LDS buffer (no barrier needed).
// ---------------------------------------------------------------------------
__global__ __launch_bounds__(256) void attn_k(
    const short* __restrict__ Q, const short* __restrict__ K,
    const short* __restrict__ V, short* __restrict__ Ctx)
{
    __shared__ short Kl[2][64][64];
    __shared__ short Vl[2][64][64];
    __shared__ short Pl[4][16][64];
    const int t = threadIdx.x;
    const int qt = blockIdx.x, bh = blockIdx.y;
    const int lane = t & 63, w = t >> 6;
    const int lm = lane & 15, lg = lane >> 4;
    const int swz = (lm & 7) << 3;          // P-buffer swizzle (shorts)
    const int swc = lm & 7;                 // K/V read chunk swizzle

    // Q fragment: A[q][k], lane row = lm, k = ks*32 + lg*8 + j
    const int qrow = qt * 64 + w * 16 + lm;
    short8 qf[2];
    #pragma unroll
    for (int ks = 0; ks < 2; ++ks)
        qf[ks] = *(const short8*)(Q + ((size_t)bh * 2048 + qrow) * 64 + ks * 32 + lg * 8);

    float m_run = -3e38f, l_run = 0.f;
    f32x4 o_acc[4] = {};

    // --- staging geometry: thread t handles rows r0 and r0+32, chunk c0 ---
    const int r0 = t >> 3, c0 = t & 7;
    const short* Kbase = K + ((size_t)bh * 2048) * 64;
    const short* Vbase = V + ((size_t)bh * 64) * 2048;
    const int cs = ((c0 ^ (r0 & 7)) * 8);            // swizzled chunk (shorts)
    const int lds0 = r0 * 64 + cs, lds1 = (r0 + 32) * 64 + cs;  // (r0+32)&7==r0&7

    // prologue: stage tile 0 into buffer 0
    {
        short8 ka0 = *(const short8*)(Kbase + (r0) * 64 + c0 * 8);
        short8 ka1 = *(const short8*)(Kbase + (r0 + 32) * 64 + c0 * 8);
        short8 va0 = *(const short8*)(Vbase + (size_t)r0 * 2048 + c0 * 8);
        short8 va1 = *(const short8*)(Vbase + (size_t)(r0 + 32) * 2048 + c0 * 8);
        *(short8*)((short*)Kl[0] + lds0) = ka0;
        *(short8*)((short*)Kl[0] + lds1) = ka1;
        *(short8*)((short*)Vl[0] + lds0) = va0;
        *(short8*)((short*)Vl[0] + lds1) = va1;
    }

    short* prow = &Pl[w][lm][0];
    int cur = 0;

    for (int kt = 0; kt < 32; ++kt) {
        __syncthreads();   // stage[cur] visible; prev tile's readers done with [cur^1]

        // ---- early-issue global loads for tile kt+1 ----
        short8 kn0, kn1, vn0, vn1;
        const bool pfn = (kt + 1 < 32);
        if (pfn) {
            const int kv1 = (kt + 1) * 64;
            kn0 = *(const short8*)(Kbase + (size_t)(kv1 + r0) * 64 + c0 * 8);
            kn1 = *(const short8*)(Kbase + (size_t)(kv1 + r0 + 32) * 64 + c0 * 8);
            vn0 = *(const short8*)(Vbase + (size_t)r0 * 2048 + kv1 + c0 * 8);
            vn1 = *(const short8*)(Vbase + (size_t)(r0 + 32) * 2048 + kv1 + c0 * 8);
        }

        const short* Kc = (const short*)Kl[cur];
        const short* Vc = (const short*)Vl[cur];

        // ---- S^T = K Q^T : lane holds q=lm, keys nf*16 + lg*4 + i ----
        f32x4 sa[4] = {};
        #pragma unroll
        for (int nf = 0; nf < 4; ++nf) {
            const int rr = nf * 16 + lm;
            #pragma unroll
            for (int ks = 0; ks < 2; ++ks) {
                const short8 kf = *(const short8*)(Kc + rr * 64 + ((ks * 4 + lg) ^ swc) * 8);
                sa[nf] = __builtin_amdgcn_mfma_f32_16x16x32_bf16(kf, qf[ks], sa[nf], 0, 0, 0);
            }
        }

        // ---- online softmax, per-lane row (q = lm) ----
        float mt = sa[0][0];
        #pragma unroll
        for (int nf = 0; nf < 4; ++nf)
            #pragma unroll
            for (int i = 0; i < 4; ++i)
                mt = fmaxf(mt, sa[nf][i]);
        mt = fmaxf(mt, __shfl_xor(mt, 16));
        mt = fmaxf(mt, __shfl_xor(mt, 32));
        const float mn = fmaxf(m_run, mt);
        const float alpha = __expf(m_run - mn);
        float rs = 0.f;
        #pragma unroll
        for (int nf = 0; nf < 4; ++nf)
            #pragma unroll
            for (int i = 0; i < 4; ++i) {
                const float e = __expf(sa[nf][i] - mn);
                sa[nf][i] = e;
                rs += e;
            }
        rs += __shfl_xor(rs, 16);
        rs += __shfl_xor(rs, 32);
        l_run = l_run * alpha + rs;
        m_run = mn;
        #pragma unroll
        for (int nf = 0; nf < 4; ++nf)
            #pragma unroll
            for (int i = 0; i < 4; ++i)
                o_acc[nf][i] *= alpha;

        // ---- P^T -> per-wave swizzled LDS, read back as B-frag ----
        #pragma unroll
        for (int nf = 0; nf < 4; ++nf) {
            uint2 pv;
            pv.x = pk_bf16(sa[nf][0], sa[nf][1]);
            pv.y = pk_bf16(sa[nf][2], sa[nf][3]);
            *(uint2*)(prow + ((nf * 16 + lg * 4) ^ swz)) = pv;
        }
        short8 pf[2];
        #pragma unroll
        for (int ks = 0; ks < 2; ++ks)
            pf[ks] = *(const short8*)(prow + ((ks * 32 + lg * 8) ^ swz));

        // ---- late ds_write of tile kt+1 into the other buffer ----
        if (pfn) {
            short* Kn = (short*)Kl[cur ^ 1];
            short* Vn = (short*)Vl[cur ^ 1];
            *(short8*)(Kn + lds0) = kn0;
            *(short8*)(Kn + lds1) = kn1;
            *(short8*)(Vn + lds0) = vn0;
            *(short8*)(Vn + lds1) = vn1;
        }

        // ---- ctx^T += V^T P^T : lane holds q=lm, d = nf*16 + lg*4 + i ----
        #pragma unroll
        for (int nf = 0; nf < 4; ++nf) {
            const int rr = nf * 16 + lm;
            #pragma unroll
            for (int ks = 0; ks < 2; ++ks) {
                const short8 vf = *(const short8*)(Vc + rr * 64 + ((ks * 4 + lg) ^ swc) * 8);
                o_acc[nf] = __builtin_amdgcn_mfma_f32_16x16x32_bf16(vf, pf[ks], o_acc[nf], 0, 0, 0);
            }
        }
        cur ^= 1;
    }

    // epilogue: ctx[b][q][h*64 + d], d = nf*16 + lg*4 + i -> 8B vector writes
    const float inv = 1.f / l_run;
    const int b = bh >> 4, h = bh & 15;
    short* outp = Ctx + ((size_t)b * 2048 + qrow) * 1024 + h * 64 + lg * 4;
    #pragma unroll
    for (int nf = 0; nf < 4; ++nf) {
        uint2 pk;
        pk.x = pk_bf16(o_acc[nf][0] * inv, o_acc[nf][1] * inv);
        pk.y = pk_bf16(o_acc[nf][2] * inv, o_acc[nf][3] * inv);
        *(uint2*)(outp + nf * 16) = pk;
    }
}

// ---------------------------------------------------------------------------
extern "C" void kernel_launch(void* const* d_in, const int* in_sizes, int n_in,
                              void* d_out, int out_size, void* d_ws, size_t ws_size,
                              hipStream_t stream)
{
    const float* query  = (const float*)d_in[0];
    const float* key_in = (const float*)d_in[1];
    const float* value  = (const float*)d_in[2];
    const float* Wq = (const float*)d_in[3];
    const float* bq = (const float*)d_in[4];
    const float* Wk = (const float*)d_in[5];
    const float* bk = (const float*)d_in[6];
    const float* Wv = (const float*)d_in[7];
    const float* bv = (const float*)d_in[8];
    const float* Wo = (const float*)d_in[9];
    const float* bo = (const float*)d_in[10];
    float* out = (float*)d_out;

    char* ws = (char*)d_ws;
    short* Wt  = (short*)(ws);              // 4 x 2MB bf16 transposed weights
    short* Qh  = (short*)(ws + (8  << 20)); // [B,H,S,64]  8MB (pre-scaled 1/8)
    short* Kh  = (short*)(ws + (16 << 20)); // [B,H,S,64]  8MB
    short* Vt  = (short*)(ws + (24 << 20)); // [B,H,64,S]  8MB
    short* Ctx = (short*)(ws + (32 << 20)); // [B,S,D]     8MB

    hipLaunchKernelGGL(wtrans, dim3(32, 32, 4), dim3(32, 8), 0, stream,
                       Wq, Wk, Wv, Wo, Wt);
    hipLaunchKernelGGL((gemm_k<0, 0>), dim3(32, 8), dim3(256), 0, stream,
                       query, Wt, bq, Qh, 0.125f);
    hipLaunchKernelGGL((gemm_k<0, 0>), dim3(32, 8), dim3(256), 0, stream,
                       key_in, Wt + (1 << 20), bk, Kh, 1.0f);
    hipLaunchKernelGGL((gemm_k<0, 1>), dim3(32, 8), dim3(256), 0, stream,
                       value, Wt + (2 << 20), bv, Vt, 1.0f);
    hipLaunchKernelGGL(attn_k, dim3(32, 32), dim3(256), 0, stream,
                       Qh, Kh, Vt, Ctx);
    hipLaunchKernelGGL((gemm_k<1, 2>), dim3(32, 8), dim3(256), 0, stream,
                       Ctx, Wt + (3 << 20), bo, out, 1.0f);
}

// Round 4
// 200.651 us; speedup vs baseline: 1.8179x; 1.0516x over previous
//
#include <hip/hip_runtime.h>
#include <hip/hip_bf16.h>

// Problem constants: B=2, S=2048, D=1024, H=16, HD=64, M = B*S = 4096

typedef __attribute__((ext_vector_type(8))) short short8;   // 8 bf16 = 4 VGPR
typedef __attribute__((ext_vector_type(4))) short short4v;  // 4 bf16
typedef __attribute__((ext_vector_type(4))) float f32x4;    // MFMA C/D frag

static __device__ __forceinline__ short f2bf(float f) {
    union { float f; unsigned u; } c; c.f = f;
    unsigned r = c.u + 0x7fff + ((c.u >> 16) & 1);   // RNE
    return (short)(r >> 16);
}

// packed f32x2 -> bf16x2 (v_cvt_pk_bf16_f32)
static __device__ __forceinline__ unsigned pk_bf16(float a, float b) {
    union { __hip_bfloat162 h; unsigned u; } c;
    c.h = __float22bfloat162_rn(make_float2(a, b));
    return c.u;
}

// async global -> LDS, 16B per lane (global_load_lds_dwordx4).
// LDS dest is wave-uniform base + lane*16; global src is per-lane.
typedef const void __attribute__((address_space(1)))* gas_ptr;
typedef void __attribute__((address_space(3)))* las_ptr;
static __device__ __forceinline__ void gload16(const void* g, void* l) {
    __builtin_amdgcn_global_load_lds((gas_ptr)g, (las_ptr)l, 16, 0, 0);
}

// ---------------------------------------------------------------------------
// f32 -> bf16 conversion for the 3 activation inputs (4M elems each).
// ---------------------------------------------------------------------------
__global__ __launch_bounds__(256) void tobf16(
    const float* __restrict__ X0, const float* __restrict__ X1,
    const float* __restrict__ X2, short* __restrict__ O)
{
    const float* X = blockIdx.y == 0 ? X0 : blockIdx.y == 1 ? X1 : X2;
    short* o = O + ((size_t)blockIdx.y << 22);
    const int i = (blockIdx.x * 256 + threadIdx.x) * 8;
    const float4 a = *(const float4*)(X + i);
    const float4 b = *(const float4*)(X + i + 4);
    uint4 r;
    r.x = pk_bf16(a.x, a.y); r.y = pk_bf16(a.z, a.w);
    r.z = pk_bf16(b.x, b.y); r.w = pk_bf16(b.z, b.w);
    *(uint4*)(o + i) = r;
}

// ---------------------------------------------------------------------------
// Weight transpose + bf16 cast: W[K=1024][N=1024] f32 -> Wt[N][K] bf16.
// ---------------------------------------------------------------------------
__global__ __launch_bounds__(256) void wtrans(
    const float* __restrict__ W0, const float* __restrict__ W1,
    const float* __restrict__ W2, const float* __restrict__ W3,
    short* __restrict__ Out)
{
    const float* W = blockIdx.z == 0 ? W0 : blockIdx.z == 1 ? W1
                   : blockIdx.z == 2 ? W2 : W3;
    short* O = Out + ((size_t)blockIdx.z << 20);
    __shared__ float tile[32][33];
    const int k0 = blockIdx.x * 32, n0 = blockIdx.y * 32;
    const int tx = threadIdx.x, ty = threadIdx.y;  // (32,8)
    #pragma unroll
    for (int j = 0; j < 32; j += 8)
        tile[ty + j][tx] = W[(k0 + ty + j) * 1024 + n0 + tx];
    __syncthreads();
    #pragma unroll
    for (int j = 0; j < 32; j += 8)
        O[(n0 + ty + j) * 1024 + k0 + tx] = f2bf(tile[tx][ty + j]);
}

// ---------------------------------------------------------------------------
// GEMM v2: Out = scale * (A @ Wt^T + bias), A bf16 [4096][1024], Wt [N][K] bf16.
// 128x128 tile, BK=32, 4 waves x (64x64 = 4x4 frags of 16x16x32).
// Double-buffered LDS staged via global_load_lds dwordx4 (16B/lane), 2-phase
// schedule: STAGE(next buf) issued BEFORE compute(cur); single barrier per
// K-step (compiler drains vmcnt+lgkmcnt at the barrier — loads hide under
// the ds_read+MFMA phase). Linear LDS [128][32] (m97 structure).
// OMODE: 0 = bf16 head-split [B,H,S,64] (Q pre-scaled, K)
//        1 = bf16 transposed [B,H,64,S] (V)
//        2 = f32 flat [4096][1024] (final output)
// ---------------------------------------------------------------------------
template<int OMODE>
__global__ __launch_bounds__(256) void gemm2(
    const short* __restrict__ Aa, const short* __restrict__ Ba,
    const float* __restrict__ bias, void* __restrict__ Out, float scale)
{
    __shared__ short Al[2][4096];   // [128 m][32 k] bf16, chunk-linear
    __shared__ short Bl[2][4096];   // [128 n][32 k]
    const int t = threadIdx.x;
    const int m0 = blockIdx.x * 128, n0 = blockIdx.y * 128;
    const int lane = t & 63, w = t >> 6;
    const int lm = lane & 15, lg = lane >> 4;
    const int wr = w >> 1, wc = w & 1;

    f32x4 acc[4][4] = {};

    // stage tile at k0 into buffer buf: 512 chunks of 16B per matrix,
    // chunk c -> row c>>2, k-chunk c&3; wave w covers chunks [j*256+w*64 .. +63]
    #define STAGE(buf, k0) do {                                               \
        _Pragma("unroll")                                                     \
        for (int j = 0; j < 2; ++j) {                                         \
            const int c = j * 256 + w * 64 + lane;                            \
            gload16(Aa + (size_t)(m0 + (c >> 2)) * 1024 + (k0) + (c & 3) * 8, \
                    &Al[buf][j * 2048 + w * 512]);                            \
            gload16(Ba + (size_t)(n0 + (c >> 2)) * 1024 + (k0) + (c & 3) * 8, \
                    &Bl[buf][j * 2048 + w * 512]);                            \
        }                                                                     \
    } while (0)

    STAGE(0, 0);
    __syncthreads();

    int buf = 0;
    for (int kk = 0; kk < 32; ++kk) {
        if (kk < 31) STAGE(buf ^ 1, (kk + 1) * 32);

        const short* Ab = Al[buf];
        const short* Bb = Bl[buf];
        short8 af[4], bfr[4];
        #pragma unroll
        for (int mf = 0; mf < 4; ++mf)
            af[mf] = *(const short8*)(Ab + (wr * 64 + mf * 16 + lm) * 32 + lg * 8);
        #pragma unroll
        for (int nf = 0; nf < 4; ++nf)
            bfr[nf] = *(const short8*)(Bb + (wc * 64 + nf * 16 + lm) * 32 + lg * 8);
        #pragma unroll
        for (int mf = 0; mf < 4; ++mf)
            #pragma unroll
            for (int nf = 0; nf < 4; ++nf)
                acc[mf][nf] = __builtin_amdgcn_mfma_f32_16x16x32_bf16(
                    af[mf], bfr[nf], acc[mf][nf], 0, 0, 0);

        __syncthreads();     // drains vmcnt (staged loads) + lgkmcnt
        buf ^= 1;
    }
    #undef STAGE

    // epilogue — D frag: col = lm (n), rows = lg*4 + i (m)
    #pragma unroll
    for (int mf = 0; mf < 4; ++mf) {
        const int mb = m0 + wr * 64 + mf * 16 + lg * 4;
        #pragma unroll
        for (int nf = 0; nf < 4; ++nf) {
            const int n = n0 + wc * 64 + nf * 16 + lm;
            const float bs = bias[n];
            if (OMODE == 2) {
                float* O = (float*)Out;
                #pragma unroll
                for (int i = 0; i < 4; ++i)
                    O[(mb + i) * 1024 + n] = scale * (acc[mf][nf][i] + bs);
            } else if (OMODE == 0) {
                short* O = (short*)Out;
                #pragma unroll
                for (int i = 0; i < 4; ++i) {
                    const int m = mb + i;
                    const int addr = (((m >> 11) * 16 + (n >> 6)) * 2048 + (m & 2047)) * 64 + (n & 63);
                    O[addr] = f2bf(scale * (acc[mf][nf][i] + bs));
                }
            } else {  // OMODE 1: Vt [B,H,64,S]
                short* O = (short*)Out;
                short4v sv;
                #pragma unroll
                for (int i = 0; i < 4; ++i)
                    sv[i] = f2bf(scale * (acc[mf][nf][i] + bs));
                const int addr = (((mb >> 11) * 16 + (n >> 6)) * 64 + (n & 63)) * 2048 + (mb & 2047);
                *(short4v*)&O[addr] = sv;
            }
        }
    }
}

// ---------------------------------------------------------------------------
// Flash attention (round-3 structure + exp2-domain softmax + defer-max + T5).
// Q[B,H,S,64] (pre-scaled by 0.125*log2e), K[B,H,S,64], V^T[B,H,64,S], bf16.
// Block = 64 q-rows x one bh; 4 waves x 16 q-rows; KVBLK=64; double-buffered
// K/V LDS (XOR chunk-swizzle both sides), 1 barrier/tile, T14 early-issue
// loads. Swapped QK^T / PV: per-lane online softmax (2 shfl_xor per reduce).
// ---------------------------------------------------------------------------
__global__ __launch_bounds__(256) void attn_k(
    const short* __restrict__ Q, const short* __restrict__ K,
    const short* __restrict__ V, short* __restrict__ Ctx)
{
    __shared__ short Kl[2][64][64];
    __shared__ short Vl[2][64][64];
    __shared__ short Pl[4][16][64];
    const int t = threadIdx.x;
    const int qt = blockIdx.x, bh = blockIdx.y;
    const int lane = t & 63, w = t >> 6;
    const int lm = lane & 15, lg = lane >> 4;
    const int swz = (lm & 7) << 3;          // P-buffer swizzle (shorts)
    const int swc = lm & 7;                 // K/V read chunk swizzle

    const int qrow = qt * 64 + w * 16 + lm;
    short8 qf[2];
    #pragma unroll
    for (int ks = 0; ks < 2; ++ks)
        qf[ks] = *(const short8*)(Q + ((size_t)bh * 2048 + qrow) * 64 + ks * 32 + lg * 8);

    float m_run = -3e38f, l_run = 0.f;
    f32x4 o_acc[4] = {};

    const int r0 = t >> 3, c0 = t & 7;
    const short* Kbase = K + ((size_t)bh * 2048) * 64;
    const short* Vbase = V + ((size_t)bh * 64) * 2048;
    const int cs = ((c0 ^ (r0 & 7)) * 8);
    const int lds0 = r0 * 64 + cs, lds1 = (r0 + 32) * 64 + cs;

    {   // prologue: stage tile 0 into buffer 0
        short8 ka0 = *(const short8*)(Kbase + (r0) * 64 + c0 * 8);
        short8 ka1 = *(const short8*)(Kbase + (r0 + 32) * 64 + c0 * 8);
        short8 va0 = *(const short8*)(Vbase + (size_t)r0 * 2048 + c0 * 8);
        short8 va1 = *(const short8*)(Vbase + (size_t)(r0 + 32) * 2048 + c0 * 8);
        *(short8*)((short*)Kl[0] + lds0) = ka0;
        *(short8*)((short*)Kl[0] + lds1) = ka1;
        *(short8*)((short*)Vl[0] + lds0) = va0;
        *(short8*)((short*)Vl[0] + lds1) = va1;
    }

    short* prow = &Pl[w][lm][0];
    int cur = 0;

    for (int kt = 0; kt < 32; ++kt) {
        __syncthreads();

        // early-issue global loads for tile kt+1 (T14)
        short8 kn0, kn1, vn0, vn1;
        const bool pfn = (kt + 1 < 32);
        if (pfn) {
            const int kv1 = (kt + 1) * 64;
            kn0 = *(const short8*)(Kbase + (size_t)(kv1 + r0) * 64 + c0 * 8);
            kn1 = *(const short8*)(Kbase + (size_t)(kv1 + r0 + 32) * 64 + c0 * 8);
            vn0 = *(const short8*)(Vbase + (size_t)r0 * 2048 + kv1 + c0 * 8);
            vn1 = *(const short8*)(Vbase + (size_t)(r0 + 32) * 2048 + kv1 + c0 * 8);
        }

        const short* Kc = (const short*)Kl[cur];
        const short* Vc = (const short*)Vl[cur];

        // S^T = K Q^T : lane holds q=lm, keys nf*16 + lg*4 + i  (log2 domain)
        f32x4 sa[4] = {};
        __builtin_amdgcn_s_setprio(1);
        #pragma unroll
        for (int nf = 0; nf < 4; ++nf) {
            const int rr = nf * 16 + lm;
            #pragma unroll
            for (int ks = 0; ks < 2; ++ks) {
                const short8 kf = *(const short8*)(Kc + rr * 64 + ((ks * 4 + lg) ^ swc) * 8);
                sa[nf] = __builtin_amdgcn_mfma_f32_16x16x32_bf16(kf, qf[ks], sa[nf], 0, 0, 0);
            }
        }
        __builtin_amdgcn_s_setprio(0);

        // ---- online softmax in exp2 domain, per-lane row (q = lm) ----
        float mt = sa[0][0];
        #pragma unroll
        for (int nf = 0; nf < 4; ++nf)
            #pragma unroll
            for (int i = 0; i < 4; ++i)
                mt = fmaxf(mt, sa[nf][i]);
        mt = fmaxf(mt, __shfl_xor(mt, 16));
        mt = fmaxf(mt, __shfl_xor(mt, 32));
        // defer-max (T13): only rescale when the running max grew by > 8
        if (__any(mt > m_run + 8.0f)) {
            const float mn = fmaxf(m_run, mt);
            const float alpha = exp2f(m_run - mn);
            l_run *= alpha;
            #pragma unroll
            for (int nf = 0; nf < 4; ++nf)
                #pragma unroll
                for (int i = 0; i < 4; ++i)
                    o_acc[nf][i] *= alpha;
            m_run = mn;
        }
        float rs = 0.f;
        #pragma unroll
        for (int nf = 0; nf < 4; ++nf)
            #pragma unroll
            for (int i = 0; i < 4; ++i) {
                const float e = exp2f(sa[nf][i] - m_run);
                sa[nf][i] = e;
                rs += e;
            }
        rs += __shfl_xor(rs, 16);
        rs += __shfl_xor(rs, 32);
        l_run += rs;

        // P^T -> per-wave swizzled LDS, read back as B-frag
        #pragma unroll
        for (int nf = 0; nf < 4; ++nf) {
            uint2 pv;
            pv.x = pk_bf16(sa[nf][0], sa[nf][1]);
            pv.y = pk_bf16(sa[nf][2], sa[nf][3]);
            *(uint2*)(prow + ((nf * 16 + lg * 4) ^ swz)) = pv;
        }
        short8 pf[2];
        #pragma unroll
        for (int ks = 0; ks < 2; ++ks)
            pf[ks] = *(const short8*)(prow + ((ks * 32 + lg * 8) ^ swz));

        // late ds_write of tile kt+1 into the other buffer
        if (pfn) {
            short* Kn = (short*)Kl[cur ^ 1];
            short* Vn = (short*)Vl[cur ^ 1];
            *(short8*)(Kn + lds0) = kn0;
            *(short8*)(Kn + lds1) = kn1;
            *(short8*)(Vn + lds0) = vn0;
            *(short8*)(Vn + lds1) = vn1;
        }

        // ctx^T += V^T P^T : lane holds q=lm, d = nf*16 + lg*4 + i
        __builtin_amdgcn_s_setprio(1);
        #pragma unroll
        for (int nf = 0; nf < 4; ++nf) {
            const int rr = nf * 16 + lm;
            #pragma unroll
            for (int ks = 0; ks < 2; ++ks) {
                const short8 vf = *(const short8*)(Vc + rr * 64 + ((ks * 4 + lg) ^ swc) * 8);
                o_acc[nf] = __builtin_amdgcn_mfma_f32_16x16x32_bf16(vf, pf[ks], o_acc[nf], 0, 0, 0);
            }
        }
        __builtin_amdgcn_s_setprio(0);
        cur ^= 1;
    }

    // epilogue: ctx[b][q][h*64 + d] bf16, 8B vector writes
    const float inv = 1.f / l_run;
    const int b = bh >> 4, h = bh & 15;
    short* outp = Ctx + ((size_t)b * 2048 + qrow) * 1024 + h * 64 + lg * 4;
    #pragma unroll
    for (int nf = 0; nf < 4; ++nf) {
        uint2 pk;
        pk.x = pk_bf16(o_acc[nf][0] * inv, o_acc[nf][1] * inv);
        pk.y = pk_bf16(o_acc[nf][2] * inv, o_acc[nf][3] * inv);
        *(uint2*)(outp + nf * 16) = pk;
    }
}

// ---------------------------------------------------------------------------
extern "C" void kernel_launch(void* const* d_in, const int* in_sizes, int n_in,
                              void* d_out, int out_size, void* d_ws, size_t ws_size,
                              hipStream_t stream)
{
    const float* query  = (const float*)d_in[0];
    const float* key_in = (const float*)d_in[1];
    const float* value  = (const float*)d_in[2];
    const float* Wq = (const float*)d_in[3];
    const float* bq = (const float*)d_in[4];
    const float* Wk = (const float*)d_in[5];
    const float* bk = (const float*)d_in[6];
    const float* Wv = (const float*)d_in[7];
    const float* bv = (const float*)d_in[8];
    const float* Wo = (const float*)d_in[9];
    const float* bo = (const float*)d_in[10];
    float* out = (float*)d_out;

    char* ws = (char*)d_ws;
    short* Wt  = (short*)(ws);               // 4 x 2MB transposed bf16 weights
    short* Abf = (short*)(ws + (8  << 20));  // 3 x 8MB bf16 inputs (q,k,v)
    short* Qh  = (short*)(ws + (32 << 20));  // [B,H,S,64] 8MB (scaled 0.125*log2e)
    short* Kh  = (short*)(ws + (40 << 20));  // [B,H,S,64] 8MB
    short* Vt  = (short*)(ws + (48 << 20));  // [B,H,64,S] 8MB
    short* Ctx = Abf;                        // Abf dead after V-gemm; alias

    const float qscale = 0.125f * 1.44269504088896f;  // fold 1/sqrt(64) * log2(e)

    hipLaunchKernelGGL(tobf16, dim3(2048, 3), dim3(256), 0, stream,
                       query, key_in, value, Abf);
    hipLaunchKernelGGL(wtrans, dim3(32, 32, 4), dim3(32, 8), 0, stream,
                       Wq, Wk, Wv, Wo, Wt);
    hipLaunchKernelGGL((gemm2<0>), dim3(32, 8), dim3(256), 0, stream,
                       Abf,             Wt,             bq, Qh, qscale);
    hipLaunchKernelGGL((gemm2<0>), dim3(32, 8), dim3(256), 0, stream,
                       Abf + (1 << 22), Wt + (1 << 20), bk, Kh, 1.0f);
    hipLaunchKernelGGL((gemm2<1>), dim3(32, 8), dim3(256), 0, stream,
                       Abf + (2 << 22), Wt + (2 << 20), bv, Vt, 1.0f);
    hipLaunchKernelGGL(attn_k, dim3(32, 32), dim3(256), 0, stream,
                       Qh, Kh, Vt, Ctx);
    hipLaunchKernelGGL((gemm2<2>), dim3(32, 8), dim3(256), 0, stream,
                       Ctx, Wt + (3 << 20), bo, out, 1.0f);
}

// Round 5
// 176.077 us; speedup vs baseline: 2.0716x; 1.1396x over previous
//
#include <hip/hip_runtime.h>
#include <hip/hip_bf16.h>

// Problem constants: B=2, S=2048, D=1024, H=16, HD=64, M = B*S = 4096

typedef __attribute__((ext_vector_type(8))) short short8;   // 8 bf16 = 4 VGPR
typedef __attribute__((ext_vector_type(4))) short short4v;  // 4 bf16
typedef __attribute__((ext_vector_type(4))) float f32x4;    // MFMA C/D frag

static __device__ __forceinline__ short f2bf(float f) {
    union { float f; unsigned u; } c; c.f = f;
    unsigned r = c.u + 0x7fff + ((c.u >> 16) & 1);   // RNE
    return (short)(r >> 16);
}

// packed f32x2 -> bf16x2 (v_cvt_pk_bf16_f32)
static __device__ __forceinline__ unsigned pk_bf16(float a, float b) {
    union { __hip_bfloat162 h; unsigned u; } c;
    c.h = __float22bfloat162_rn(make_float2(a, b));
    return c.u;
}

// async global -> LDS, 16B per lane (global_load_lds_dwordx4).
typedef const void __attribute__((address_space(1)))* gas_ptr;
typedef void __attribute__((address_space(3)))* las_ptr;
static __device__ __forceinline__ void gload16(const void* g, void* l) {
    __builtin_amdgcn_global_load_lds((gas_ptr)g, (las_ptr)l, 16, 0, 0);
}

// ---------------------------------------------------------------------------
// prep: merged f32->bf16 input conversion (3 x 4M elems) + weight transpose
// (4 x W[K][N] f32 -> Wt[N][K] bf16). One dispatch, 10240 blocks.
// ---------------------------------------------------------------------------
__global__ __launch_bounds__(256) void prep(
    const float* __restrict__ X0, const float* __restrict__ X1,
    const float* __restrict__ X2, short* __restrict__ Abf,
    const float* __restrict__ W0, const float* __restrict__ W1,
    const float* __restrict__ W2, const float* __restrict__ W3,
    short* __restrict__ Wt)
{
    __shared__ float tile[32][33];
    const int bid = blockIdx.x;
    if (bid < 6144) {           // --- tobf16: 2048 blocks per input ---
        const int zz = bid >> 11, xb = bid & 2047;
        const float* X = zz == 0 ? X0 : zz == 1 ? X1 : X2;
        short* o = Abf + ((size_t)zz << 22);
        const int i = (xb * 256 + threadIdx.x) * 8;
        const float4 a = *(const float4*)(X + i);
        const float4 b = *(const float4*)(X + i + 4);
        uint4 r;
        r.x = pk_bf16(a.x, a.y); r.y = pk_bf16(a.z, a.w);
        r.z = pk_bf16(b.x, b.y); r.w = pk_bf16(b.z, b.w);
        *(uint4*)(o + i) = r;
    } else {                    // --- wtrans: 1024 blocks per weight ---
        const int wid = bid - 6144;
        const int z = wid >> 10;
        const float* W = z == 0 ? W0 : z == 1 ? W1 : z == 2 ? W2 : W3;
        short* O = Wt + ((size_t)z << 20);
        const int k0 = (wid & 31) * 32, n0 = ((wid >> 5) & 31) * 32;
        const int tx = threadIdx.x & 31, ty = threadIdx.x >> 5;  // (32,8)
        #pragma unroll
        for (int j = 0; j < 32; j += 8)
            tile[ty + j][tx] = W[(k0 + ty + j) * 1024 + n0 + tx];
        __syncthreads();
        #pragma unroll
        for (int j = 0; j < 32; j += 8)
            O[(n0 + ty + j) * 1024 + k0 + tx] = f2bf(tile[tx][ty + j]);
    }
}

// ---------------------------------------------------------------------------
// GEMM core geometry (BM=64, BN=128, BK=32), 4 waves:
// wave w owns rows wr*32 (wr=w>>1), cols wc*64 (wc=w&1): acc[2][4] frags.
// Double-buffered LDS via global_load_lds dwordx4; STAGE(next) before
// compute(cur); one barrier per K-step. Grid x = n-tile (adjacent blocks
// share the A-panel), y = m-tile. 512 blocks per GEMM instance.
// ---------------------------------------------------------------------------
#define GEMM_CORE(Aa, Ba)                                                     \
    __shared__ short Al[2][2048];   /* [64 m][32 k] */                        \
    __shared__ short Bl[2][4096];   /* [128 n][32 k] */                       \
    const int t = threadIdx.x;                                                \
    const int m0 = blockIdx.y * 64, n0 = blockIdx.x * 128;                    \
    const int lane = t & 63, w = t >> 6;                                      \
    const int lm = lane & 15, lg = lane >> 4;                                 \
    const int wr = w >> 1, wc = w & 1;                                        \
    f32x4 acc[2][4] = {};                                                     \
    STAGE(0, 0);                                                              \
    __syncthreads();                                                          \
    int buf = 0;                                                              \
    for (int kk = 0; kk < 32; ++kk) {                                         \
        if (kk < 31) STAGE(buf ^ 1, (kk + 1) * 32);                           \
        const short* Ab = Al[buf];                                            \
        const short* Bb = Bl[buf];                                            \
        short8 af[2], bfr[4];                                                 \
        _Pragma("unroll")                                                     \
        for (int mf = 0; mf < 2; ++mf)                                        \
            af[mf] = *(const short8*)(Ab + (wr * 32 + mf * 16 + lm) * 32 + lg * 8); \
        _Pragma("unroll")                                                     \
        for (int nf = 0; nf < 4; ++nf)                                        \
            bfr[nf] = *(const short8*)(Bb + (wc * 64 + nf * 16 + lm) * 32 + lg * 8); \
        _Pragma("unroll")                                                     \
        for (int mf = 0; mf < 2; ++mf)                                        \
            _Pragma("unroll")                                                 \
            for (int nf = 0; nf < 4; ++nf)                                    \
                acc[mf][nf] = __builtin_amdgcn_mfma_f32_16x16x32_bf16(        \
                    af[mf], bfr[nf], acc[mf][nf], 0, 0, 0);                   \
        __syncthreads();                                                      \
        buf ^= 1;                                                             \
    }

#define STAGE(buf, k0) do {                                                   \
    gload16(Aa + (size_t)(m0 + (t >> 2)) * 1024 + (k0) + (t & 3) * 8,         \
            &Al[buf][w * 512]);                                               \
    _Pragma("unroll")                                                         \
    for (int j = 0; j < 2; ++j) {                                             \
        const int c = j * 256 + t;                                            \
        gload16(Ba + (size_t)(n0 + (c >> 2)) * 1024 + (k0) + (c & 3) * 8,     \
                &Bl[buf][j * 2048 + w * 512]);                                \
    }                                                                         \
} while (0)

// ---------------------------------------------------------------------------
// Merged Q/K/V projection GEMM: blockIdx.z selects (A, W, bias, out, scale).
// z=0: Q = qscale*(q@Wq^T + bq) -> head-split [B,H,S,64]
// z=1: K ->  head-split [B,H,S,64]
// z=2: V ->  transposed [B,H,64,S]
// Grid (8, 64, 3) = 1536 blocks = 6 blocks/CU (LDS 24KB).
// ---------------------------------------------------------------------------
__global__ __launch_bounds__(256) void gemmqkv(
    const short* __restrict__ Abase, const short* __restrict__ Wt,
    const float* __restrict__ bq, const float* __restrict__ bk,
    const float* __restrict__ bv, short* __restrict__ Qh,
    short* __restrict__ Kh, short* __restrict__ Vt, float qscale)
{
    const int z = blockIdx.z;
    const short* Aa = Abase + ((size_t)z << 22);
    const short* Ba = Wt + ((size_t)z << 20);
    const float* bias = z == 0 ? bq : z == 1 ? bk : bv;
    short* O = z == 0 ? Qh : z == 1 ? Kh : Vt;
    const float scale = z == 0 ? qscale : 1.0f;

    GEMM_CORE(Aa, Ba)

    // epilogue — D frag: col = lm (n), rows = lg*4 + i (m)
    #pragma unroll
    for (int mf = 0; mf < 2; ++mf) {
        const int mb = m0 + wr * 32 + mf * 16 + lg * 4;
        #pragma unroll
        for (int nf = 0; nf < 4; ++nf) {
            const int n = n0 + wc * 64 + nf * 16 + lm;
            const float bs = bias[n];
            if (z == 2) {   // V^T [B,H,64,S]: 4 consecutive s per lane
                short4v sv;
                #pragma unroll
                for (int i = 0; i < 4; ++i)
                    sv[i] = f2bf(acc[mf][nf][i] + bs);
                const int addr = (((mb >> 11) * 16 + (n >> 6)) * 64 + (n & 63)) * 2048 + (mb & 2047);
                *(short4v*)&O[addr] = sv;
            } else {        // head-split [B,H,S,64]
                #pragma unroll
                for (int i = 0; i < 4; ++i) {
                    const int m = mb + i;
                    const int addr = (((m >> 11) * 16 + (n >> 6)) * 2048 + (m & 2047)) * 64 + (n & 63);
                    O[addr] = f2bf(scale * (acc[mf][nf][i] + bs));
                }
            }
        }
    }
}

// ---------------------------------------------------------------------------
// Final projection: out = Ctx @ Wo^T + bo, f32 flat [4096][1024].
// Grid (8, 64) = 512 blocks = 2 blocks/CU.
// ---------------------------------------------------------------------------
__global__ __launch_bounds__(256) void gemmo(
    const short* __restrict__ Aa, const short* __restrict__ Ba,
    const float* __restrict__ bias, float* __restrict__ Out)
{
    GEMM_CORE(Aa, Ba)

    #pragma unroll
    for (int mf = 0; mf < 2; ++mf) {
        const int mb = m0 + wr * 32 + mf * 16 + lg * 4;
        #pragma unroll
        for (int nf = 0; nf < 4; ++nf) {
            const int n = n0 + wc * 64 + nf * 16 + lm;
            const float bs = bias[n];
            #pragma unroll
            for (int i = 0; i < 4; ++i)
                Out[(mb + i) * 1024 + n] = acc[mf][nf][i] + bs;
        }
    }
}
#undef STAGE
#undef GEMM_CORE

// ---------------------------------------------------------------------------
// Flash attention (round-3 structure + exp2-domain softmax + defer-max; NO
// setprio — lockstep 4-wave blocks are the m190 null/negative regime).
// Q[B,H,S,64] (pre-scaled by 0.125*log2e), K[B,H,S,64], V^T[B,H,64,S], bf16.
// Block = 64 q-rows x one bh; 4 waves x 16 q-rows; KVBLK=64; double-buffered
// K/V LDS (XOR chunk-swizzle both sides), 1 barrier/tile, T14 early-issue
// loads. Swapped QK^T / PV: per-lane online softmax (2 shfl_xor per reduce).
// ---------------------------------------------------------------------------
__global__ __launch_bounds__(256) void attn_k(
    const short* __restrict__ Q, const short* __restrict__ K,
    const short* __restrict__ V, short* __restrict__ Ctx)
{
    __shared__ short Kl[2][64][64];
    __shared__ short Vl[2][64][64];
    __shared__ short Pl[4][16][64];
    const int t = threadIdx.x;
    const int qt = blockIdx.x, bh = blockIdx.y;
    const int lane = t & 63, w = t >> 6;
    const int lm = lane & 15, lg = lane >> 4;
    const int swz = (lm & 7) << 3;          // P-buffer swizzle (shorts)
    const int swc = lm & 7;                 // K/V read chunk swizzle

    const int qrow = qt * 64 + w * 16 + lm;
    short8 qf[2];
    #pragma unroll
    for (int ks = 0; ks < 2; ++ks)
        qf[ks] = *(const short8*)(Q + ((size_t)bh * 2048 + qrow) * 64 + ks * 32 + lg * 8);

    float m_run = -3e38f, l_run = 0.f;
    f32x4 o_acc[4] = {};

    const int r0 = t >> 3, c0 = t & 7;
    const short* Kbase = K + ((size_t)bh * 2048) * 64;
    const short* Vbase = V + ((size_t)bh * 64) * 2048;
    const int cs = ((c0 ^ (r0 & 7)) * 8);
    const int lds0 = r0 * 64 + cs, lds1 = (r0 + 32) * 64 + cs;

    {   // prologue: stage tile 0 into buffer 0
        short8 ka0 = *(const short8*)(Kbase + (r0) * 64 + c0 * 8);
        short8 ka1 = *(const short8*)(Kbase + (r0 + 32) * 64 + c0 * 8);
        short8 va0 = *(const short8*)(Vbase + (size_t)r0 * 2048 + c0 * 8);
        short8 va1 = *(const short8*)(Vbase + (size_t)(r0 + 32) * 2048 + c0 * 8);
        *(short8*)((short*)Kl[0] + lds0) = ka0;
        *(short8*)((short*)Kl[0] + lds1) = ka1;
        *(short8*)((short*)Vl[0] + lds0) = va0;
        *(short8*)((short*)Vl[0] + lds1) = va1;
    }

    short* prow = &Pl[w][lm][0];
    int cur = 0;

    for (int kt = 0; kt < 32; ++kt) {
        __syncthreads();

        // early-issue global loads for tile kt+1 (T14)
        short8 kn0, kn1, vn0, vn1;
        const bool pfn = (kt + 1 < 32);
        if (pfn) {
            const int kv1 = (kt + 1) * 64;
            kn0 = *(const short8*)(Kbase + (size_t)(kv1 + r0) * 64 + c0 * 8);
            kn1 = *(const short8*)(Kbase + (size_t)(kv1 + r0 + 32) * 64 + c0 * 8);
            vn0 = *(const short8*)(Vbase + (size_t)r0 * 2048 + kv1 + c0 * 8);
            vn1 = *(const short8*)(Vbase + (size_t)(r0 + 32) * 2048 + kv1 + c0 * 8);
        }

        const short* Kc = (const short*)Kl[cur];
        const short* Vc = (const short*)Vl[cur];

        // S^T = K Q^T : lane holds q=lm, keys nf*16 + lg*4 + i  (log2 domain)
        f32x4 sa[4] = {};
        #pragma unroll
        for (int nf = 0; nf < 4; ++nf) {
            const int rr = nf * 16 + lm;
            #pragma unroll
            for (int ks = 0; ks < 2; ++ks) {
                const short8 kf = *(const short8*)(Kc + rr * 64 + ((ks * 4 + lg) ^ swc) * 8);
                sa[nf] = __builtin_amdgcn_mfma_f32_16x16x32_bf16(kf, qf[ks], sa[nf], 0, 0, 0);
            }
        }

        // ---- online softmax in exp2 domain, per-lane row (q = lm) ----
        float mt = sa[0][0];
        #pragma unroll
        for (int nf = 0; nf < 4; ++nf)
            #pragma unroll
            for (int i = 0; i < 4; ++i)
                mt = fmaxf(mt, sa[nf][i]);
        mt = fmaxf(mt, __shfl_xor(mt, 16));
        mt = fmaxf(mt, __shfl_xor(mt, 32));
        // defer-max (T13): only rescale when the running max grew by > 8
        if (__any(mt > m_run + 8.0f)) {
            const float mn = fmaxf(m_run, mt);
            const float alpha = exp2f(m_run - mn);
            l_run *= alpha;
            #pragma unroll
            for (int nf = 0; nf < 4; ++nf)
                #pragma unroll
                for (int i = 0; i < 4; ++i)
                    o_acc[nf][i] *= alpha;
            m_run = mn;
        }
        float rs = 0.f;
        #pragma unroll
        for (int nf = 0; nf < 4; ++nf)
            #pragma unroll
            for (int i = 0; i < 4; ++i) {
                const float e = exp2f(sa[nf][i] - m_run);
                sa[nf][i] = e;
                rs += e;
            }
        rs += __shfl_xor(rs, 16);
        rs += __shfl_xor(rs, 32);
        l_run += rs;

        // P^T -> per-wave swizzled LDS, read back as B-frag
        #pragma unroll
        for (int nf = 0; nf < 4; ++nf) {
            uint2 pv;
            pv.x = pk_bf16(sa[nf][0], sa[nf][1]);
            pv.y = pk_bf16(sa[nf][2], sa[nf][3]);
            *(uint2*)(prow + ((nf * 16 + lg * 4) ^ swz)) = pv;
        }
        short8 pf[2];
        #pragma unroll
        for (int ks = 0; ks < 2; ++ks)
            pf[ks] = *(const short8*)(prow + ((ks * 32 + lg * 8) ^ swz));

        // late ds_write of tile kt+1 into the other buffer
        if (pfn) {
            short* Kn = (short*)Kl[cur ^ 1];
            short* Vn = (short*)Vl[cur ^ 1];
            *(short8*)(Kn + lds0) = kn0;
            *(short8*)(Kn + lds1) = kn1;
            *(short8*)(Vn + lds0) = vn0;
            *(short8*)(Vn + lds1) = vn1;
        }

        // ctx^T += V^T P^T : lane holds q=lm, d = nf*16 + lg*4 + i
        #pragma unroll
        for (int nf = 0; nf < 4; ++nf) {
            const int rr = nf * 16 + lm;
            #pragma unroll
            for (int ks = 0; ks < 2; ++ks) {
                const short8 vf = *(const short8*)(Vc + rr * 64 + ((ks * 4 + lg) ^ swc) * 8);
                o_acc[nf] = __builtin_amdgcn_mfma_f32_16x16x32_bf16(vf, pf[ks], o_acc[nf], 0, 0, 0);
            }
        }
        cur ^= 1;
    }

    // epilogue: ctx[b][q][h*64 + d] bf16, 8B vector writes
    const float inv = 1.f / l_run;
    const int b = bh >> 4, h = bh & 15;
    short* outp = Ctx + ((size_t)b * 2048 + qrow) * 1024 + h * 64 + lg * 4;
    #pragma unroll
    for (int nf = 0; nf < 4; ++nf) {
        uint2 pk;
        pk.x = pk_bf16(o_acc[nf][0] * inv, o_acc[nf][1] * inv);
        pk.y = pk_bf16(o_acc[nf][2] * inv, o_acc[nf][3] * inv);
        *(uint2*)(outp + nf * 16) = pk;
    }
}

// ---------------------------------------------------------------------------
extern "C" void kernel_launch(void* const* d_in, const int* in_sizes, int n_in,
                              void* d_out, int out_size, void* d_ws, size_t ws_size,
                              hipStream_t stream)
{
    const float* query  = (const float*)d_in[0];
    const float* key_in = (const float*)d_in[1];
    const float* value  = (const float*)d_in[2];
    const float* Wq = (const float*)d_in[3];
    const float* bq = (const float*)d_in[4];
    const float* Wk = (const float*)d_in[5];
    const float* bk = (const float*)d_in[6];
    const float* Wv = (const float*)d_in[7];
    const float* bv = (const float*)d_in[8];
    const float* Wo = (const float*)d_in[9];
    const float* bo = (const float*)d_in[10];
    float* out = (float*)d_out;

    char* ws = (char*)d_ws;
    short* Wt  = (short*)(ws);               // 4 x 2MB transposed bf16 weights
    short* Abf = (short*)(ws + (8  << 20));  // 3 x 8MB bf16 inputs (q,k,v)
    short* Qh  = (short*)(ws + (32 << 20));  // [B,H,S,64] 8MB (scaled 0.125*log2e)
    short* Kh  = (short*)(ws + (40 << 20));  // [B,H,S,64] 8MB
    short* Vt  = (short*)(ws + (48 << 20));  // [B,H,64,S] 8MB
    short* Ctx = Abf;                        // Abf dead after QKV gemm; alias

    const float qscale = 0.125f * 1.44269504088896f;  // 1/sqrt(64) * log2(e)

    hipLaunchKernelGGL(prep, dim3(10240), dim3(256), 0, stream,
                       query, key_in, value, Abf, Wq, Wk, Wv, Wo, Wt);
    hipLaunchKernelGGL(gemmqkv, dim3(8, 64, 3), dim3(256), 0, stream,
                       Abf, Wt, bq, bk, bv, Qh, Kh, Vt, qscale);
    hipLaunchKernelGGL(attn_k, dim3(32, 32), dim3(256), 0, stream,
                       Qh, Kh, Vt, Ctx);
    hipLaunchKernelGGL(gemmo, dim3(8, 64), dim3(256), 0, stream,
                       Ctx, Wt + (3 << 20), bo, out);
}

// Round 6
// 163.134 us; speedup vs baseline: 2.2360x; 1.0793x over previous
//
#include <hip/hip_runtime.h>
#include <hip/hip_bf16.h>

// Problem constants: B=2, S=2048, D=1024, H=16, HD=64, M = B*S = 4096

typedef __attribute__((ext_vector_type(8))) short short8;   // 8 bf16 = 4 VGPR
typedef __attribute__((ext_vector_type(4))) short short4v;  // 4 bf16
typedef __attribute__((ext_vector_type(4))) float f32x4;    // MFMA C/D frag

static __device__ __forceinline__ short f2bf(float f) {
    union { float f; unsigned u; } c; c.f = f;
    unsigned r = c.u + 0x7fff + ((c.u >> 16) & 1);   // RNE
    return (short)(r >> 16);
}

// packed f32x2 -> bf16x2 (v_cvt_pk_bf16_f32)
static __device__ __forceinline__ unsigned pk_bf16(float a, float b) {
    union { __hip_bfloat162 h; unsigned u; } c;
    c.h = __float22bfloat162_rn(make_float2(a, b));
    return c.u;
}

// async global -> LDS, 16B per lane (global_load_lds_dwordx4).
typedef const void __attribute__((address_space(1)))* gas_ptr;
typedef void __attribute__((address_space(3)))* las_ptr;
static __device__ __forceinline__ void gload16(const void* g, void* l) {
    __builtin_amdgcn_global_load_lds((gas_ptr)g, (las_ptr)l, 16, 0, 0);
}

// ---------------------------------------------------------------------------
// prep: merged f32->bf16 input conversion (3 x 4M elems) + weight transpose
// (4 x W[K][N] f32 -> Wt[N][K] bf16). One dispatch, 10240 blocks.
// ---------------------------------------------------------------------------
__global__ __launch_bounds__(256) void prep(
    const float* __restrict__ X0, const float* __restrict__ X1,
    const float* __restrict__ X2, short* __restrict__ Abf,
    const float* __restrict__ W0, const float* __restrict__ W1,
    const float* __restrict__ W2, const float* __restrict__ W3,
    short* __restrict__ Wt)
{
    __shared__ float tile[32][33];
    const int bid = blockIdx.x;
    if (bid < 6144) {           // --- tobf16: 2048 blocks per input ---
        const int zz = bid >> 11, xb = bid & 2047;
        const float* X = zz == 0 ? X0 : zz == 1 ? X1 : X2;
        short* o = Abf + ((size_t)zz << 22);
        const int i = (xb * 256 + threadIdx.x) * 8;
        const float4 a = *(const float4*)(X + i);
        const float4 b = *(const float4*)(X + i + 4);
        uint4 r;
        r.x = pk_bf16(a.x, a.y); r.y = pk_bf16(a.z, a.w);
        r.z = pk_bf16(b.x, b.y); r.w = pk_bf16(b.z, b.w);
        *(uint4*)(o + i) = r;
    } else {                    // --- wtrans: 1024 blocks per weight ---
        const int wid = bid - 6144;
        const int z = wid >> 10;
        const float* W = z == 0 ? W0 : z == 1 ? W1 : z == 2 ? W2 : W3;
        short* O = Wt + ((size_t)z << 20);
        const int k0 = (wid & 31) * 32, n0 = ((wid >> 5) & 31) * 32;
        const int tx = threadIdx.x & 31, ty = threadIdx.x >> 5;  // (32,8)
        #pragma unroll
        for (int j = 0; j < 32; j += 8)
            tile[ty + j][tx] = W[(k0 + ty + j) * 1024 + n0 + tx];
        __syncthreads();
        #pragma unroll
        for (int j = 0; j < 32; j += 8)
            O[(n0 + ty + j) * 1024 + k0 + tx] = f2bf(tile[tx][ty + j]);
    }
}

// ---------------------------------------------------------------------------
// GEMM core geometry (BM=64, BN=128, BK=32), 4 waves:
// wave w owns rows wr*32 (wr=w>>1), cols wc*64 (wc=w&1): acc[2][4] frags.
// Double-buffered LDS via global_load_lds dwordx4; STAGE(next) before
// compute(cur); one barrier per K-step. Grid x = n-tile (adjacent blocks
// share the A-panel), y = m-tile.
// ---------------------------------------------------------------------------
#define GEMM_CORE(Aa, Ba)                                                     \
    __shared__ short Al[2][2048];   /* [64 m][32 k] */                        \
    __shared__ short Bl[2][4096];   /* [128 n][32 k] */                       \
    const int t = threadIdx.x;                                                \
    const int m0 = blockIdx.y * 64, n0 = blockIdx.x * 128;                    \
    const int lane = t & 63, w = t >> 6;                                      \
    const int lm = lane & 15, lg = lane >> 4;                                 \
    const int wr = w >> 1, wc = w & 1;                                        \
    f32x4 acc[2][4] = {};                                                     \
    STAGE(0, 0);                                                              \
    __syncthreads();                                                          \
    int buf = 0;                                                              \
    for (int kk = 0; kk < 32; ++kk) {                                         \
        if (kk < 31) STAGE(buf ^ 1, (kk + 1) * 32);                           \
        const short* Ab = Al[buf];                                            \
        const short* Bb = Bl[buf];                                            \
        short8 af[2], bfr[4];                                                 \
        _Pragma("unroll")                                                     \
        for (int mf = 0; mf < 2; ++mf)                                        \
            af[mf] = *(const short8*)(Ab + (wr * 32 + mf * 16 + lm) * 32 + lg * 8); \
        _Pragma("unroll")                                                     \
        for (int nf = 0; nf < 4; ++nf)                                        \
            bfr[nf] = *(const short8*)(Bb + (wc * 64 + nf * 16 + lm) * 32 + lg * 8); \
        _Pragma("unroll")                                                     \
        for (int mf = 0; mf < 2; ++mf)                                        \
            _Pragma("unroll")                                                 \
            for (int nf = 0; nf < 4; ++nf)                                    \
                acc[mf][nf] = __builtin_amdgcn_mfma_f32_16x16x32_bf16(        \
                    af[mf], bfr[nf], acc[mf][nf], 0, 0, 0);                   \
        __syncthreads();                                                      \
        buf ^= 1;                                                             \
    }

#define STAGE(buf, k0) do {                                                   \
    gload16(Aa + (size_t)(m0 + (t >> 2)) * 1024 + (k0) + (t & 3) * 8,         \
            &Al[buf][w * 512]);                                               \
    _Pragma("unroll")                                                         \
    for (int j = 0; j < 2; ++j) {                                             \
        const int c = j * 256 + t;                                            \
        gload16(Ba + (size_t)(n0 + (c >> 2)) * 1024 + (k0) + (c & 3) * 8,     \
                &Bl[buf][j * 2048 + w * 512]);                                \
    }                                                                         \
} while (0)

// ---------------------------------------------------------------------------
// Merged Q/K/V projection GEMM: blockIdx.z selects (A, W, bias, out, scale).
// Grid (8, 64, 3) = 1536 blocks = 6 blocks/CU (LDS 24KB).
// ---------------------------------------------------------------------------
__global__ __launch_bounds__(256) void gemmqkv(
    const short* __restrict__ Abase, const short* __restrict__ Wt,
    const float* __restrict__ bq, const float* __restrict__ bk,
    const float* __restrict__ bv, short* __restrict__ Qh,
    short* __restrict__ Kh, short* __restrict__ Vt, float qscale)
{
    const int z = blockIdx.z;
    const short* Aa = Abase + ((size_t)z << 22);
    const short* Ba = Wt + ((size_t)z << 20);
    const float* bias = z == 0 ? bq : z == 1 ? bk : bv;
    short* O = z == 0 ? Qh : z == 1 ? Kh : Vt;
    const float scale = z == 0 ? qscale : 1.0f;

    GEMM_CORE(Aa, Ba)

    // epilogue — D frag: col = lm (n), rows = lg*4 + i (m)
    #pragma unroll
    for (int mf = 0; mf < 2; ++mf) {
        const int mb = m0 + wr * 32 + mf * 16 + lg * 4;
        #pragma unroll
        for (int nf = 0; nf < 4; ++nf) {
            const int n = n0 + wc * 64 + nf * 16 + lm;
            const float bs = bias[n];
            if (z == 2) {   // V^T [B,H,64,S]: 4 consecutive s per lane
                short4v sv;
                #pragma unroll
                for (int i = 0; i < 4; ++i)
                    sv[i] = f2bf(acc[mf][nf][i] + bs);
                const int addr = (((mb >> 11) * 16 + (n >> 6)) * 64 + (n & 63)) * 2048 + (mb & 2047);
                *(short4v*)&O[addr] = sv;
            } else {        // head-split [B,H,S,64]
                #pragma unroll
                for (int i = 0; i < 4; ++i) {
                    const int m = mb + i;
                    const int addr = (((m >> 11) * 16 + (n >> 6)) * 2048 + (m & 2047)) * 64 + (n & 63);
                    O[addr] = f2bf(scale * (acc[mf][nf][i] + bs));
                }
            }
        }
    }
}

// ---------------------------------------------------------------------------
// Final projection: out = Ctx @ Wo^T + bo, f32 flat [4096][1024].
// Grid (8, 64) = 512 blocks = 2 blocks/CU.
// ---------------------------------------------------------------------------
__global__ __launch_bounds__(256) void gemmo(
    const short* __restrict__ Aa, const short* __restrict__ Ba,
    const float* __restrict__ bias, float* __restrict__ Out)
{
    GEMM_CORE(Aa, Ba)

    #pragma unroll
    for (int mf = 0; mf < 2; ++mf) {
        const int mb = m0 + wr * 32 + mf * 16 + lg * 4;
        #pragma unroll
        for (int nf = 0; nf < 4; ++nf) {
            const int n = n0 + wc * 64 + nf * 16 + lm;
            const float bs = bias[n];
            #pragma unroll
            for (int i = 0; i < 4; ++i)
                Out[(mb + i) * 1024 + n] = acc[mf][nf][i] + bs;
        }
    }
}
#undef STAGE
#undef GEMM_CORE

// ---------------------------------------------------------------------------
// Flash attention v5: 8 waves x 16 q-rows = 128 q-rows/block; KVBLK=128 per
// barrier (two 64-key compute halves inside one staging iteration).
// Q[B,H,S,64] (pre-scaled 0.125*log2e), K[B,H,S,64], V^T[B,H,64,S], bf16.
// - staging per query halves (128 q share each K/V tile vs 64 before)
// - barriers 32 -> 16 per block; loop overhead halves
// - K tile [128][64], V^T tile [64][128], double-buffered, XOR chunk-swizzle
//   (chunk ^= row&7 within each 8-chunk group) on write AND read
// - T14: next tile's global loads issue at top; ds_writes land between the
//   two compute halves
// - swapped QK^T / PV (verified r3-r5): per-lane online softmax, exp2
//   domain, defer-max (T13); P via per-wave swizzled LDS (no barrier)
// LDS 80KB -> 2 blocks/CU; VGPR ~95 (launch_bounds 512,4) -> 16 waves/CU.
// ---------------------------------------------------------------------------
__global__ __launch_bounds__(512, 4) void attn_k(
    const short* __restrict__ Q, const short* __restrict__ K,
    const short* __restrict__ V, short* __restrict__ Ctx)
{
    __shared__ short Kl[2][128][64];
    __shared__ short Vl[2][64][128];
    __shared__ short Pl[8][16][64];
    const int t = threadIdx.x;
    const int qt = blockIdx.x, bh = blockIdx.y;
    const int lane = t & 63, w = t >> 6;   // 8 waves
    const int lm = lane & 15, lg = lane >> 4;
    const int swz = (lm & 7) << 3;          // P-buffer swizzle (shorts)
    const int swc = lm & 7;                 // K/V read chunk swizzle

    const int qrow = qt * 128 + w * 16 + lm;
    short8 qf[2];
    #pragma unroll
    for (int ks = 0; ks < 2; ++ks)
        qf[ks] = *(const short8*)(Q + ((size_t)bh * 2048 + qrow) * 64 + ks * 32 + lg * 8);

    float m_run = -3e38f, l_run = 0.f;
    f32x4 o_acc[4] = {};

    // staging: thread t owns K row rk chunks {2ck, 2ck+1} and V row rv
    // chunks {2cv, 2cv+1} (16B chunks)
    const int rk = t >> 2, ck = t & 3;
    const int rv = t >> 3, cv = t & 7;
    const short* Kg = K + ((size_t)bh * 2048 + rk) * 64 + ck * 16;
    const short* Vg = V + ((size_t)bh * 64 + rv) * 2048 + cv * 16;
    const int koff0 = rk * 64 + ((ck * 2) ^ (rk & 7)) * 8;
    const int koff1 = rk * 64 + ((ck * 2 + 1) ^ (rk & 7)) * 8;
    const int vc0 = cv * 2, vc1 = cv * 2 + 1;
    const int voff0 = rv * 128 + ((vc0 & 8) | ((vc0 & 7) ^ (rv & 7))) * 8;
    const int voff1 = rv * 128 + ((vc1 & 8) | ((vc1 & 7) ^ (rv & 7))) * 8;

    {   // prologue: stage tile 0 into buffer 0
        short8 a = *(const short8*)(Kg);
        short8 b = *(const short8*)(Kg + 8);
        short8 c = *(const short8*)(Vg);
        short8 d = *(const short8*)(Vg + 8);
        *(short8*)((short*)Kl[0] + koff0) = a;
        *(short8*)((short*)Kl[0] + koff1) = b;
        *(short8*)((short*)Vl[0] + voff0) = c;
        *(short8*)((short*)Vl[0] + voff1) = d;
    }

    short* prow = &Pl[w][lm][0];
    int cur = 0;

    for (int kt = 0; kt < 16; ++kt) {
        __syncthreads();   // stage[cur] visible; [cur^1] free for writing

        // early-issue global loads for tile kt+1 (T14)
        short8 kn0, kn1, vn0, vn1;
        const bool pfn = (kt < 15);
        if (pfn) {
            const short* Kgn = Kg + (size_t)(kt + 1) * 8192;   // 128 rows * 64
            const short* Vgn = Vg + (kt + 1) * 128;
            kn0 = *(const short8*)(Kgn);
            kn1 = *(const short8*)(Kgn + 8);
            vn0 = *(const short8*)(Vgn);
            vn1 = *(const short8*)(Vgn + 8);
        }

        const short* Kc = (const short*)Kl[cur];
        const short* Vc = (const short*)Vl[cur];

        #pragma unroll
        for (int h = 0; h < 2; ++h) {
            // ---- S^T = K Q^T : lane holds q=lm, keys h*64 + nf*16+lg*4+i ----
            f32x4 sa[4] = {};
            #pragma unroll
            for (int nf = 0; nf < 4; ++nf) {
                const int rr = h * 64 + nf * 16 + lm;
                #pragma unroll
                for (int ks = 0; ks < 2; ++ks) {
                    const short8 kf = *(const short8*)(Kc + rr * 64 + ((ks * 4 + lg) ^ swc) * 8);
                    sa[nf] = __builtin_amdgcn_mfma_f32_16x16x32_bf16(kf, qf[ks], sa[nf], 0, 0, 0);
                }
            }

            // ---- online softmax (exp2 domain), per-lane row (q = lm) ----
            float mt = sa[0][0];
            #pragma unroll
            for (int nf = 0; nf < 4; ++nf)
                #pragma unroll
                for (int i = 0; i < 4; ++i)
                    mt = fmaxf(mt, sa[nf][i]);
            mt = fmaxf(mt, __shfl_xor(mt, 16));
            mt = fmaxf(mt, __shfl_xor(mt, 32));
            if (__any(mt > m_run + 8.0f)) {     // defer-max (T13)
                const float mn = fmaxf(m_run, mt);
                const float alpha = exp2f(m_run - mn);
                l_run *= alpha;
                #pragma unroll
                for (int nf = 0; nf < 4; ++nf)
                    #pragma unroll
                    for (int i = 0; i < 4; ++i)
                        o_acc[nf][i] *= alpha;
                m_run = mn;
            }
            float rs = 0.f;
            #pragma unroll
            for (int nf = 0; nf < 4; ++nf)
                #pragma unroll
                for (int i = 0; i < 4; ++i) {
                    const float e = exp2f(sa[nf][i] - m_run);
                    sa[nf][i] = e;
                    rs += e;
                }
            rs += __shfl_xor(rs, 16);
            rs += __shfl_xor(rs, 32);
            l_run += rs;

            // ---- P^T -> per-wave swizzled LDS, read back as B-frag ----
            #pragma unroll
            for (int nf = 0; nf < 4; ++nf) {
                uint2 pv;
                pv.x = pk_bf16(sa[nf][0], sa[nf][1]);
                pv.y = pk_bf16(sa[nf][2], sa[nf][3]);
                *(uint2*)(prow + ((nf * 16 + lg * 4) ^ swz)) = pv;
            }
            short8 pf[2];
            #pragma unroll
            for (int ks = 0; ks < 2; ++ks)
                pf[ks] = *(const short8*)(prow + ((ks * 32 + lg * 8) ^ swz));

            // ---- late ds_write of tile kt+1 (between the two halves) ----
            if (h == 0 && pfn) {
                short* Kn = (short*)Kl[cur ^ 1];
                short* Vn = (short*)Vl[cur ^ 1];
                *(short8*)(Kn + koff0) = kn0;
                *(short8*)(Kn + koff1) = kn1;
                *(short8*)(Vn + voff0) = vn0;
                *(short8*)(Vn + voff1) = vn1;
            }

            // ---- ctx^T += V^T P^T : lane holds q=lm, d = nf*16+lg*4+i ----
            #pragma unroll
            for (int nf = 0; nf < 4; ++nf) {
                const int rr = nf * 16 + lm;
                #pragma unroll
                for (int ks = 0; ks < 2; ++ks) {
                    const short8 vf = *(const short8*)(Vc + rr * 128 + (h * 8 + ((ks * 4 + lg) ^ swc)) * 8);
                    o_acc[nf] = __builtin_amdgcn_mfma_f32_16x16x32_bf16(vf, pf[ks], o_acc[nf], 0, 0, 0);
                }
            }
        }
        cur ^= 1;
    }

    // epilogue: ctx[b][q][h*64 + d] bf16, 8B vector writes
    const float inv = 1.f / l_run;
    const int b = bh >> 4, h = bh & 15;
    short* outp = Ctx + ((size_t)b * 2048 + qrow) * 1024 + h * 64 + lg * 4;
    #pragma unroll
    for (int nf = 0; nf < 4; ++nf) {
        uint2 pk;
        pk.x = pk_bf16(o_acc[nf][0] * inv, o_acc[nf][1] * inv);
        pk.y = pk_bf16(o_acc[nf][2] * inv, o_acc[nf][3] * inv);
        *(uint2*)(outp + nf * 16) = pk;
    }
}

// ---------------------------------------------------------------------------
extern "C" void kernel_launch(void* const* d_in, const int* in_sizes, int n_in,
                              void* d_out, int out_size, void* d_ws, size_t ws_size,
                              hipStream_t stream)
{
    const float* query  = (const float*)d_in[0];
    const float* key_in = (const float*)d_in[1];
    const float* value  = (const float*)d_in[2];
    const float* Wq = (const float*)d_in[3];
    const float* bq = (const float*)d_in[4];
    const float* Wk = (const float*)d_in[5];
    const float* bk = (const float*)d_in[6];
    const float* Wv = (const float*)d_in[7];
    const float* bv = (const float*)d_in[8];
    const float* Wo = (const float*)d_in[9];
    const float* bo = (const float*)d_in[10];
    float* out = (float*)d_out;

    char* ws = (char*)d_ws;
    short* Wt  = (short*)(ws);               // 4 x 2MB transposed bf16 weights
    short* Abf = (short*)(ws + (8  << 20));  // 3 x 8MB bf16 inputs (q,k,v)
    short* Qh  = (short*)(ws + (32 << 20));  // [B,H,S,64] 8MB (scaled 0.125*log2e)
    short* Kh  = (short*)(ws + (40 << 20));  // [B,H,S,64] 8MB
    short* Vt  = (short*)(ws + (48 << 20));  // [B,H,64,S] 8MB
    short* Ctx = Abf;                        // Abf dead after QKV gemm; alias

    const float qscale = 0.125f * 1.44269504088896f;  // 1/sqrt(64) * log2(e)

    hipLaunchKernelGGL(prep, dim3(10240), dim3(256), 0, stream,
                       query, key_in, value, Abf, Wq, Wk, Wv, Wo, Wt);
    hipLaunchKernelGGL(gemmqkv, dim3(8, 64, 3), dim3(256), 0, stream,
                       Abf, Wt, bq, bk, bv, Qh, Kh, Vt, qscale);
    hipLaunchKernelGGL(attn_k, dim3(16, 32), dim3(512), 0, stream,
                       Qh, Kh, Vt, Ctx);
    hipLaunchKernelGGL(gemmo, dim3(8, 64), dim3(256), 0, stream,
                       Ctx, Wt + (3 << 20), bo, out);
}

// Round 7
// 161.289 us; speedup vs baseline: 2.2616x; 1.0114x over previous
//
#include <hip/hip_runtime.h>
#include <hip/hip_bf16.h>

// Problem constants: B=2, S=2048, D=1024, H=16, HD=64, M = B*S = 4096

typedef __attribute__((ext_vector_type(8))) short short8;   // 8 bf16 = 4 VGPR
typedef __attribute__((ext_vector_type(4))) short short4v;  // 4 bf16
typedef __attribute__((ext_vector_type(4))) float f32x4;    // MFMA C/D frag

static __device__ __forceinline__ short f2bf(float f) {
    union { float f; unsigned u; } c; c.f = f;
    unsigned r = c.u + 0x7fff + ((c.u >> 16) & 1);   // RNE
    return (short)(r >> 16);
}

// packed f32x2 -> bf16x2 (v_cvt_pk_bf16_f32)
static __device__ __forceinline__ unsigned pk_bf16(float a, float b) {
    union { __hip_bfloat162 h; unsigned u; } c;
    c.h = __float22bfloat162_rn(make_float2(a, b));
    return c.u;
}

// async global -> LDS, 16B per lane (global_load_lds_dwordx4).
typedef const void __attribute__((address_space(1)))* gas_ptr;
typedef void __attribute__((address_space(3)))* las_ptr;
static __device__ __forceinline__ void gload16(const void* g, void* l) {
    __builtin_amdgcn_global_load_lds((gas_ptr)g, (las_ptr)l, 16, 0, 0);
}

// ---------------------------------------------------------------------------
// prep: merged f32->bf16 input conversion (3 x 4M elems) + weight transpose
// (4 x W[K][N] f32 -> Wt[N][K] bf16). One dispatch, 10240 blocks.
// ---------------------------------------------------------------------------
__global__ __launch_bounds__(256) void prep(
    const float* __restrict__ X0, const float* __restrict__ X1,
    const float* __restrict__ X2, short* __restrict__ Abf,
    const float* __restrict__ W0, const float* __restrict__ W1,
    const float* __restrict__ W2, const float* __restrict__ W3,
    short* __restrict__ Wt)
{
    __shared__ float tile[32][33];
    const int bid = blockIdx.x;
    if (bid < 6144) {           // --- tobf16: 2048 blocks per input ---
        const int zz = bid >> 11, xb = bid & 2047;
        const float* X = zz == 0 ? X0 : zz == 1 ? X1 : X2;
        short* o = Abf + ((size_t)zz << 22);
        const int i = (xb * 256 + threadIdx.x) * 8;
        const float4 a = *(const float4*)(X + i);
        const float4 b = *(const float4*)(X + i + 4);
        uint4 r;
        r.x = pk_bf16(a.x, a.y); r.y = pk_bf16(a.z, a.w);
        r.z = pk_bf16(b.x, b.y); r.w = pk_bf16(b.z, b.w);
        *(uint4*)(o + i) = r;
    } else {                    // --- wtrans: 1024 blocks per weight ---
        const int wid = bid - 6144;
        const int z = wid >> 10;
        const float* W = z == 0 ? W0 : z == 1 ? W1 : z == 2 ? W2 : W3;
        short* O = Wt + ((size_t)z << 20);
        const int k0 = (wid & 31) * 32, n0 = ((wid >> 5) & 31) * 32;
        const int tx = threadIdx.x & 31, ty = threadIdx.x >> 5;  // (32,8)
        #pragma unroll
        for (int j = 0; j < 32; j += 8)
            tile[ty + j][tx] = W[(k0 + ty + j) * 1024 + n0 + tx];
        __syncthreads();
        #pragma unroll
        for (int j = 0; j < 32; j += 8)
            O[(n0 + ty + j) * 1024 + k0 + tx] = f2bf(tile[tx][ty + j]);
    }
}

// ---------------------------------------------------------------------------
// GEMM core geometry (BM=64, BN=128, BK=32), 4 waves:
// wave w owns rows wr*32 (wr=w>>1), cols wc*64 (wc=w&1): acc[2][4] frags.
// Double-buffered LDS via global_load_lds dwordx4; STAGE(next) before
// compute(cur); one barrier per K-step.
// ---------------------------------------------------------------------------
#define GEMM_CORE(Aa, Ba)                                                     \
    __shared__ short Al[2][2048];   /* [64 m][32 k] */                        \
    __shared__ short Bl[2][4096];   /* [128 n][32 k] */                       \
    const int t = threadIdx.x;                                                \
    const int m0 = blockIdx.y * 64, n0 = blockIdx.x * 128;                    \
    const int lane = t & 63, w = t >> 6;                                      \
    const int lm = lane & 15, lg = lane >> 4;                                 \
    const int wr = w >> 1, wc = w & 1;                                        \
    f32x4 acc[2][4] = {};                                                     \
    STAGE(0, 0);                                                              \
    __syncthreads();                                                          \
    int buf = 0;                                                              \
    for (int kk = 0; kk < 32; ++kk) {                                         \
        if (kk < 31) STAGE(buf ^ 1, (kk + 1) * 32);                           \
        const short* Ab = Al[buf];                                            \
        const short* Bb = Bl[buf];                                            \
        short8 af[2], bfr[4];                                                 \
        _Pragma("unroll")                                                     \
        for (int mf = 0; mf < 2; ++mf)                                        \
            af[mf] = *(const short8*)(Ab + (wr * 32 + mf * 16 + lm) * 32 + lg * 8); \
        _Pragma("unroll")                                                     \
        for (int nf = 0; nf < 4; ++nf)                                        \
            bfr[nf] = *(const short8*)(Bb + (wc * 64 + nf * 16 + lm) * 32 + lg * 8); \
        _Pragma("unroll")                                                     \
        for (int mf = 0; mf < 2; ++mf)                                        \
            _Pragma("unroll")                                                 \
            for (int nf = 0; nf < 4; ++nf)                                    \
                acc[mf][nf] = __builtin_amdgcn_mfma_f32_16x16x32_bf16(        \
                    af[mf], bfr[nf], acc[mf][nf], 0, 0, 0);                   \
        __syncthreads();                                                      \
        buf ^= 1;                                                             \
    }

#define STAGE(buf, k0) do {                                                   \
    gload16(Aa + (size_t)(m0 + (t >> 2)) * 1024 + (k0) + (t & 3) * 8,         \
            &Al[buf][w * 512]);                                               \
    _Pragma("unroll")                                                         \
    for (int j = 0; j < 2; ++j) {                                             \
        const int c = j * 256 + t;                                            \
        gload16(Ba + (size_t)(n0 + (c >> 2)) * 1024 + (k0) + (c & 3) * 8,     \
                &Bl[buf][j * 2048 + w * 512]);                                \
    }                                                                         \
} while (0)

// ---------------------------------------------------------------------------
// Merged Q/K/V projection GEMM. Grid (8, 64, 3) = 1536 blocks = 6/CU.
// ---------------------------------------------------------------------------
__global__ __launch_bounds__(256) void gemmqkv(
    const short* __restrict__ Abase, const short* __restrict__ Wt,
    const float* __restrict__ bq, const float* __restrict__ bk,
    const float* __restrict__ bv, short* __restrict__ Qh,
    short* __restrict__ Kh, short* __restrict__ Vt, float qscale)
{
    const int z = blockIdx.z;
    const short* Aa = Abase + ((size_t)z << 22);
    const short* Ba = Wt + ((size_t)z << 20);
    const float* bias = z == 0 ? bq : z == 1 ? bk : bv;
    short* O = z == 0 ? Qh : z == 1 ? Kh : Vt;
    const float scale = z == 0 ? qscale : 1.0f;

    GEMM_CORE(Aa, Ba)

    #pragma unroll
    for (int mf = 0; mf < 2; ++mf) {
        const int mb = m0 + wr * 32 + mf * 16 + lg * 4;
        #pragma unroll
        for (int nf = 0; nf < 4; ++nf) {
            const int n = n0 + wc * 64 + nf * 16 + lm;
            const float bs = bias[n];
            if (z == 2) {   // V^T [B,H,64,S]: 4 consecutive s per lane
                short4v sv;
                #pragma unroll
                for (int i = 0; i < 4; ++i)
                    sv[i] = f2bf(acc[mf][nf][i] + bs);
                const int addr = (((mb >> 11) * 16 + (n >> 6)) * 64 + (n & 63)) * 2048 + (mb & 2047);
                *(short4v*)&O[addr] = sv;
            } else {        // head-split [B,H,S,64]
                #pragma unroll
                for (int i = 0; i < 4; ++i) {
                    const int m = mb + i;
                    const int addr = (((m >> 11) * 16 + (n >> 6)) * 2048 + (m & 2047)) * 64 + (n & 63);
                    O[addr] = f2bf(scale * (acc[mf][nf][i] + bs));
                }
            }
        }
    }
}

// ---------------------------------------------------------------------------
// Final projection: out = Ctx @ Wo^T + bo, f32 flat. Grid (8,64) = 512 blocks.
// ---------------------------------------------------------------------------
__global__ __launch_bounds__(256) void gemmo(
    const short* __restrict__ Aa, const short* __restrict__ Ba,
    const float* __restrict__ bias, float* __restrict__ Out)
{
    GEMM_CORE(Aa, Ba)

    #pragma unroll
    for (int mf = 0; mf < 2; ++mf) {
        const int mb = m0 + wr * 32 + mf * 16 + lg * 4;
        #pragma unroll
        for (int nf = 0; nf < 4; ++nf) {
            const int n = n0 + wc * 64 + nf * 16 + lm;
            const float bs = bias[n];
            #pragma unroll
            for (int i = 0; i < 4; ++i)
                Out[(mb + i) * 1024 + n] = acc[mf][nf][i] + bs;
        }
    }
}
#undef STAGE
#undef GEMM_CORE

// ---------------------------------------------------------------------------
// Flash attention v6: 8 waves x 16 q-rows = 128 q/block, KVBLK=128/barrier.
// Changes vs v5 (both target the measured regressions):
//  - V tile stored as TWO [64][64] halves (Vl[buf][half][64][64]) — restores
//    r5's measured-clean bank pattern (128B rows + XOR chunk swizzle).
//    v5's [64][128] (256B rows) tripled SQ_LDS_BANK_CONFLICT.
//  - softmax merged across the whole 128-key tile: QK^T both halves (one
//    16-MFMA cluster), ONE max/exp/sum pass over 32 f32 (half the shuffles,
//    rescales, and T13 gates), then per-half {P-pack -> pf -> PV 8-MFMA}
//    reusing the same per-wave P buffer (wave-FIFO ds ordering, no barrier).
// Unchanged: double-buffer + T14 early loads + 1 barrier/tile; swapped
// QK^T/PV; exp2-domain softmax (Q pre-scaled 0.125*log2e); defer-max T13.
// LDS 80KB -> 2 blocks/CU.
// ---------------------------------------------------------------------------
__global__ __launch_bounds__(512, 4) void attn_k(
    const short* __restrict__ Q, const short* __restrict__ K,
    const short* __restrict__ V, short* __restrict__ Ctx)
{
    __shared__ short Kl[2][128][64];
    __shared__ short Vl[2][2][64][64];   // [buf][key-half][d-row][key-chunk]
    __shared__ short Pl[8][16][64];
    const int t = threadIdx.x;
    const int qt = blockIdx.x, bh = blockIdx.y;
    const int lane = t & 63, w = t >> 6;   // 8 waves
    const int lm = lane & 15, lg = lane >> 4;
    const int swz = (lm & 7) << 3;          // P-buffer swizzle (shorts)
    const int swc = lm & 7;                 // K/V read chunk swizzle

    const int qrow = qt * 128 + w * 16 + lm;
    short8 qf[2];
    #pragma unroll
    for (int ks = 0; ks < 2; ++ks)
        qf[ks] = *(const short8*)(Q + ((size_t)bh * 2048 + qrow) * 64 + ks * 32 + lg * 8);

    float m_run = -3e38f, l_run = 0.f;
    f32x4 o_acc[4] = {};

    // staging: thread t owns K row rk (chunks 2ck,2ck+1 of 8) and V d-row rv
    // (chunks 2cv,2cv+1 of 16; both land in key-half cv>>2)
    const int rk = t >> 2, ck = t & 3;
    const int rv = t >> 3, cv = t & 7;
    const short* Kg = K + ((size_t)bh * 2048 + rk) * 64 + ck * 16;
    const short* Vg = V + ((size_t)bh * 64 + rv) * 2048 + cv * 16;
    const int koff0 = rk * 64 + ((ck * 2) ^ (rk & 7)) * 8;
    const int koff1 = rk * 64 + ((ck * 2 + 1) ^ (rk & 7)) * 8;
    const int vhalf = (cv >> 2) * 4096;
    const int voff0 = vhalf + rv * 64 + (((cv * 2) & 7) ^ (rv & 7)) * 8;
    const int voff1 = vhalf + rv * 64 + (((cv * 2 + 1) & 7) ^ (rv & 7)) * 8;

    {   // prologue: stage tile 0 into buffer 0
        short8 a = *(const short8*)(Kg);
        short8 b = *(const short8*)(Kg + 8);
        short8 c = *(const short8*)(Vg);
        short8 d = *(const short8*)(Vg + 8);
        *(short8*)((short*)Kl[0] + koff0) = a;
        *(short8*)((short*)Kl[0] + koff1) = b;
        *(short8*)((short*)Vl[0] + voff0) = c;
        *(short8*)((short*)Vl[0] + voff1) = d;
    }

    short* prow = &Pl[w][lm][0];
    int cur = 0;

    for (int kt = 0; kt < 16; ++kt) {
        __syncthreads();   // stage[cur] visible; [cur^1] free for writing

        // early-issue global loads for tile kt+1 (T14)
        short8 kn0, kn1, vn0, vn1;
        const bool pfn = (kt < 15);
        if (pfn) {
            const short* Kgn = Kg + (size_t)(kt + 1) * 8192;   // 128 rows * 64
            const short* Vgn = Vg + (kt + 1) * 128;
            kn0 = *(const short8*)(Kgn);
            kn1 = *(const short8*)(Kgn + 8);
            vn0 = *(const short8*)(Vgn);
            vn1 = *(const short8*)(Vgn + 8);
        }

        const short* Kc = (const short*)Kl[cur];
        const short* Vc = (const short*)Vl[cur];

        // ---- S^T = K Q^T, BOTH halves: lane holds q=lm, 32 key-vals ----
        f32x4 sa[2][4] = {};
        #pragma unroll
        for (int h = 0; h < 2; ++h)
            #pragma unroll
            for (int nf = 0; nf < 4; ++nf) {
                const int rr = h * 64 + nf * 16 + lm;
                #pragma unroll
                for (int ks = 0; ks < 2; ++ks) {
                    const short8 kf = *(const short8*)(Kc + rr * 64 + ((ks * 4 + lg) ^ swc) * 8);
                    sa[h][nf] = __builtin_amdgcn_mfma_f32_16x16x32_bf16(kf, qf[ks], sa[h][nf], 0, 0, 0);
                }
            }

        // ---- ONE online-softmax pass over all 32 values (exp2 domain) ----
        float mt = sa[0][0][0];
        #pragma unroll
        for (int h = 0; h < 2; ++h)
            #pragma unroll
            for (int nf = 0; nf < 4; ++nf)
                #pragma unroll
                for (int i = 0; i < 4; ++i)
                    mt = fmaxf(mt, sa[h][nf][i]);
        mt = fmaxf(mt, __shfl_xor(mt, 16));
        mt = fmaxf(mt, __shfl_xor(mt, 32));
        if (__any(mt > m_run + 8.0f)) {     // defer-max (T13)
            const float mn = fmaxf(m_run, mt);
            const float alpha = exp2f(m_run - mn);
            l_run *= alpha;
            #pragma unroll
            for (int nf = 0; nf < 4; ++nf)
                #pragma unroll
                for (int i = 0; i < 4; ++i)
                    o_acc[nf][i] *= alpha;
            m_run = mn;
        }
        float rs = 0.f;
        #pragma unroll
        for (int h = 0; h < 2; ++h)
            #pragma unroll
            for (int nf = 0; nf < 4; ++nf)
                #pragma unroll
                for (int i = 0; i < 4; ++i) {
                    const float e = exp2f(sa[h][nf][i] - m_run);
                    sa[h][nf][i] = e;
                    rs += e;
                }
        rs += __shfl_xor(rs, 16);
        rs += __shfl_xor(rs, 32);
        l_run += rs;

        // ---- per key-half: P-pack -> pf -> PV (P buffer reused) ----
        #pragma unroll
        for (int h = 0; h < 2; ++h) {
            #pragma unroll
            for (int nf = 0; nf < 4; ++nf) {
                uint2 pv;
                pv.x = pk_bf16(sa[h][nf][0], sa[h][nf][1]);
                pv.y = pk_bf16(sa[h][nf][2], sa[h][nf][3]);
                *(uint2*)(prow + ((nf * 16 + lg * 4) ^ swz)) = pv;
            }
            short8 pf[2];
            #pragma unroll
            for (int ks = 0; ks < 2; ++ks)
                pf[ks] = *(const short8*)(prow + ((ks * 32 + lg * 8) ^ swz));

            // late ds_write of tile kt+1 (between the two PV halves)
            if (h == 0 && pfn) {
                short* Kn = (short*)Kl[cur ^ 1];
                short* Vn = (short*)Vl[cur ^ 1];
                *(short8*)(Kn + koff0) = kn0;
                *(short8*)(Kn + koff1) = kn1;
                *(short8*)(Vn + voff0) = vn0;
                *(short8*)(Vn + voff1) = vn1;
            }

            // ctx^T += V^T P^T : lane holds q=lm, d = nf*16+lg*4+i
            #pragma unroll
            for (int nf = 0; nf < 4; ++nf) {
                const int rr = nf * 16 + lm;
                #pragma unroll
                for (int ks = 0; ks < 2; ++ks) {
                    const short8 vf = *(const short8*)(Vc + h * 4096 + rr * 64 + ((ks * 4 + lg) ^ swc) * 8);
                    o_acc[nf] = __builtin_amdgcn_mfma_f32_16x16x32_bf16(vf, pf[ks], o_acc[nf], 0, 0, 0);
                }
            }
        }
        cur ^= 1;
    }

    // epilogue: ctx[b][q][h*64 + d] bf16, 8B vector writes
    const float inv = 1.f / l_run;
    const int b = bh >> 4, h = bh & 15;
    short* outp = Ctx + ((size_t)b * 2048 + qrow) * 1024 + h * 64 + lg * 4;
    #pragma unroll
    for (int nf = 0; nf < 4; ++nf) {
        uint2 pk;
        pk.x = pk_bf16(o_acc[nf][0] * inv, o_acc[nf][1] * inv);
        pk.y = pk_bf16(o_acc[nf][2] * inv, o_acc[nf][3] * inv);
        *(uint2*)(outp + nf * 16) = pk;
    }
}

// ---------------------------------------------------------------------------
extern "C" void kernel_launch(void* const* d_in, const int* in_sizes, int n_in,
                              void* d_out, int out_size, void* d_ws, size_t ws_size,
                              hipStream_t stream)
{
    const float* query  = (const float*)d_in[0];
    const float* key_in = (const float*)d_in[1];
    const float* value  = (const float*)d_in[2];
    const float* Wq = (const float*)d_in[3];
    const float* bq = (const float*)d_in[4];
    const float* Wk = (const float*)d_in[5];
    const float* bk = (const float*)d_in[6];
    const float* Wv = (const float*)d_in[7];
    const float* bv = (const float*)d_in[8];
    const float* Wo = (const float*)d_in[9];
    const float* bo = (const float*)d_in[10];
    float* out = (float*)d_out;

    char* ws = (char*)d_ws;
    short* Wt  = (short*)(ws);               // 4 x 2MB transposed bf16 weights
    short* Abf = (short*)(ws + (8  << 20));  // 3 x 8MB bf16 inputs (q,k,v)
    short* Qh  = (short*)(ws + (32 << 20));  // [B,H,S,64] 8MB (scaled 0.125*log2e)
    short* Kh  = (short*)(ws + (40 << 20));  // [B,H,S,64] 8MB
    short* Vt  = (short*)(ws + (48 << 20));  // [B,H,64,S] 8MB
    short* Ctx = Abf;                        // Abf dead after QKV gemm; alias

    const float qscale = 0.125f * 1.44269504088896f;  // 1/sqrt(64) * log2(e)

    hipLaunchKernelGGL(prep, dim3(10240), dim3(256), 0, stream,
                       query, key_in, value, Abf, Wq, Wk, Wv, Wo, Wt);
    hipLaunchKernelGGL(gemmqkv, dim3(8, 64, 3), dim3(256), 0, stream,
                       Abf, Wt, bq, bk, bv, Qh, Kh, Vt, qscale);
    hipLaunchKernelGGL(attn_k, dim3(16, 32), dim3(512), 0, stream,
                       Qh, Kh, Vt, Ctx);
    hipLaunchKernelGGL(gemmo, dim3(8, 64), dim3(256), 0, stream,
                       Ctx, Wt + (3 << 20), bo, out);
}